// Round 19
// baseline (1448.094 us; speedup 1.0000x reference)
//
#include <hip/hip_runtime.h>
#include <hip/hip_bf16.h>
#include <hip/hip_fp16.h>
#include <cstddef>

typedef _Float16 half8 __attribute__((ext_vector_type(8)));
typedef _Float16 half4 __attribute__((ext_vector_type(4)));
typedef float floatx4 __attribute__((ext_vector_type(4)));

__global__ __launch_bounds__(256) void fill_const(float* out, int n, float v) {
    int i = blockIdx.x * 256 + threadIdx.x;
    if (i < n) out[i] = v;
}

// ---------------- one-shot pack of ALL weights + x pad ----------------
__global__ __launch_bounds__(256) void pack_all(
    const float* __restrict__ wc1, const float* __restrict__ wc2,
    const float* __restrict__ wc3, const float* __restrict__ wpe,
    const float* __restrict__ wqk0, const float* __restrict__ wqk1,
    const float* __restrict__ wfc1, const float* __restrict__ wfc2,
    const float* __restrict__ wadj, const float* __restrict__ x,
    _Float16* __restrict__ wpk, _Float16* __restrict__ wadjp,
    _Float16* __restrict__ xpad)
{
    int idx = blockIdx.x * 256 + threadIdx.x;
    if (idx < 73728) {  // c1
        int i = idx;
        int j = i & 7, lane = (i >> 3) & 63, f = i >> 9;
        int t = f % 8, cc = (f / 8) % 2, k = f / 16;
        int co = t * 16 + (lane & 15);
        int ci = cc * 32 + (lane >> 4) * 8 + j;
        wpk[idx] = (_Float16)wc1[(co * 64 + ci) * 9 + k];
    } else if (idx < 155648) {  // c2
        int i = idx - 73728;
        int j = i & 7, lane = (i >> 3) & 63, f = i >> 9;
        int t = f % 8, cc = (f / 8) % 4, k = f / 32;
        int co = t * 16 + (lane & 15);
        int ci = cc * 32 + (lane >> 4) * 8 + j;
        wpk[idx] = (_Float16)wc2[(co * 128 + ci) * 5 + k];
    } else if (idx < 229376) {  // c3
        int i = idx - 155648;
        int j = i & 7, lane = (i >> 3) & 63, f = i >> 9;
        int t = f % 12, cc = (f / 12) % 4, k = f / 48;
        int co = t * 16 + (lane & 15);
        int ci = cc * 32 + (lane >> 4) * 8 + j;
        wpk[idx] = (_Float16)wc3[(co * 128 + ci) * 3 + k];
    } else if (idx < 622592) {  // pe
        int i = idx - 229376;
        int j = i & 7, lane = (i >> 3) & 63, f = i >> 9;
        int t = f % 12, cc = f / 12;
        int co = t * 16 + (lane & 15);
        int rr = cc * 32 + (lane >> 4) * 8 + j;
        int ktap = rr >> 8, ci = rr & 255;
        wpk[idx] = (_Float16)wpe[co * 2048 + ci * 8 + ktap];
    } else if (idx < 696320) {  // qk0
        int i = idx - 622592;
        int j = i & 7, lane = (i >> 3) & 63, f = i >> 9;
        int nt = f % 24, ks = f / 24;
        int c = ks * 32 + (lane >> 4) * 8 + j;
        int jcol = nt * 16 + (lane & 15);
        wpk[idx] = (_Float16)wqk0[c * 384 + jcol];
    } else if (idx < 770048) {  // qk1
        int i = idx - 696320;
        int j = i & 7, lane = (i >> 3) & 63, f = i >> 9;
        int nt = f % 24, ks = f / 24;
        int c = ks * 32 + (lane >> 4) * 8 + j;
        int jcol = nt * 16 + (lane & 15);
        wpk[idx] = (_Float16)wqk1[c * 384 + jcol];
    } else if (idx < 822272) {  // fc1 (N pad 272)
        int i = idx - 770048;
        int j = i & 7, lane = (i >> 3) & 63, f = i >> 9;
        int t = f % 17, ks = f / 17;
        int jcol = t * 16 + (lane & 15);
        int c = ks * 32 + (lane >> 4) * 8 + j;
        wpk[idx] = (jcol < 264) ? (_Float16)wfc1[c * 264 + jcol] : (_Float16)0.f;
    } else if (idx < 877568) {  // fc2 (K pad 288)
        int i = idx - 822272;
        int j = i & 7, lane = (i >> 3) & 63, f = i >> 9;
        int t = f % 12, ks = f / 12;
        int co = t * 16 + (lane & 15);
        int k = ks * 32 + (lane >> 4) * 8 + j;
        wpk[idx] = (k < 264) ? (_Float16)wfc2[k * 192 + co] : (_Float16)0.f;
    } else if (idx < 4613120) {  // adj weights (K pad 1824)
        int i = idx - 877568;
        int j = i & 7, lane = (i >> 3) & 63, f = i >> 9;
        int t = f & 127, ks = f >> 7;
        int jcol = t * 16 + (lane & 15);
        int k = ks * 32 + (lane >> 4) * 8 + j;
        wadjp[i] = (k < 1798) ? (_Float16)wadj[(size_t)k * 2048 + jcol] : (_Float16)0.f;
    } else if (idx < 5547008) {  // x pad
        int i = idx - 4613120;
        int b = i / 1824, k = i - b * 1824;
        xpad[i] = (k < 1798) ? (_Float16)x[(size_t)b * 1798 + k] : (_Float16)0.f;
    }
}

// ---------------- adj via MFMA: 512 blocks (8m x 64n), 2 n-tiles each ----------------
__global__ __launch_bounds__(256) void adj_mfma(
    const _Float16* __restrict__ xh, const _Float16* __restrict__ wp,
    const float* __restrict__ bias, _Float16* __restrict__ out)
{
    const int tid = threadIdx.x;
    const int w = tid >> 6, lane = tid & 63, quad = lane >> 4, col = lane & 15;
    const int bm = blockIdx.x >> 6;
    const int bn = blockIdx.x & 63;
    const int sample = bm * 64 + w * 16 + col;
    floatx4 acc[2];
#pragma unroll
    for (int t = 0; t < 2; ++t) acc[t] = (floatx4){0.f, 0.f, 0.f, 0.f};
    for (int ks = 0; ks < 57; ++ks) {
        half8 bf = *(const half8*)&xh[(size_t)sample * 1824 + ks * 32 + quad * 8];
#pragma unroll
        for (int tt = 0; tt < 2; ++tt) {
            int f = ks * 128 + bn * 2 + tt;
            half8 af = *(const half8*)&wp[((size_t)f * 64 + lane) * 8];
            acc[tt] = __builtin_amdgcn_mfma_f32_16x16x32_f16(af, bf, acc[tt], 0, 0, 0);
        }
    }
#pragma unroll
    for (int tt = 0; tt < 2; ++tt) {
        int jb = (bn * 2 + tt) * 16 + quad * 4;
        half4 hv;
#pragma unroll
        for (int r = 0; r < 4; ++r)
            hv[r] = (_Float16)(acc[tt][r] + bias[jb + r]);
        *(half4*)&out[(size_t)sample * 2048 + jb] = hv;
    }
}

// ---------------- c0 -> token-major [l][64] ----------------
__global__ __launch_bounds__(256) void c0_tiled(
    const _Float16* __restrict__ in, const float* __restrict__ w,
    const float* __restrict__ cb, const float* __restrict__ g,
    const float* __restrict__ bb, const float* __restrict__ m,
    const float* __restrict__ vv, _Float16* __restrict__ out)
{
    __shared__ _Float16 sin[544];
    __shared__ float wf[960], sc[64], sh[64];
    const int tid = threadIdx.x;
    const int bl = blockIdx.x >> 2;
    const int l0 = (blockIdx.x & 3) * 256;
    for (int i = tid; i < 960; i += 256) wf[i] = w[i];
    if (tid < 64) {
        float s = g[tid] * rsqrtf(vv[tid] + 1e-5f);
        sc[tid] = s;
        sh[tid] = (cb[tid] - m[tid]) * s + bb[tid];
    }
    const int base = 2 * l0 - 7;
    for (int i = tid; i < 528; i += 256) {
        int pos = base + i;
        sin[i] = (pos >= 0 && pos < 2048) ? in[(size_t)bl * 2048 + pos] : (_Float16)0.f;
    }
    __syncthreads();
    const int l = l0 + tid;
    const int s0 = 2 * tid;
    float xv[15];
#pragma unroll
    for (int k = 0; k < 15; ++k) xv[k] = (float)sin[s0 + k];
    for (int gq = 0; gq < 8; ++gq) {
        half8 ov;
#pragma unroll
        for (int r = 0; r < 8; ++r) {
            int co = gq * 8 + r;
            float acc = 0.f;
#pragma unroll
            for (int k = 0; k < 15; ++k)
                acc = fmaf(xv[k], wf[co * 15 + k], acc);
            ov[r] = (_Float16)fmaxf(fmaf(acc, sc[co], sh[co]), 0.f);
        }
        *(half8*)&out[((size_t)bl * 1024 + l) * 64 + gq * 8] = ov;
    }
}

// ---------------- conv via MFMA v2: 128-l blocks, 2 l-tiles/wave (A-frag reuse 2x) ----------------
template <int CIN, int K, int PAD, int COUT>
__global__ __launch_bounds__(256) void conv_mfma2(
    const _Float16* __restrict__ in,   // [Bc][1024][CIN]
    const _Float16* __restrict__ wp,
    const float* __restrict__ cb, const float* __restrict__ g,
    const float* __restrict__ bb, const float* __restrict__ m,
    const float* __restrict__ vv, _Float16* __restrict__ out)  // [Bc][1024][COUT]
{
    constexpr int STRIDE = (CIN == 64) ? 72 : 152;
    constexpr int LT = 128;
    constexpr int SPAN = LT + K - 1;
    constexpr int NCC = CIN / 32, NT = COUT / 16, CH8 = CIN / 8;
    __shared__ _Float16 tin[SPAN * STRIDE];
    __shared__ float sc[COUT], sh[COUT];
    const int tid = threadIdx.x;
    const int b = blockIdx.x >> 3;
    const int l0b = (blockIdx.x & 7) * LT;
    for (int c = tid; c < COUT; c += 256) {
        float s = g[c] * rsqrtf(vv[c] + 1e-5f);
        sc[c] = s;
        sh[c] = (cb[c] - m[c]) * s + bb[c];
    }
    for (int idx = tid; idx < SPAN * CH8; idx += 256) {
        int p = idx / CH8, ch = idx - p * CH8;
        int pos = l0b + p - PAD;
        half8 v = {0, 0, 0, 0, 0, 0, 0, 0};
        if (pos >= 0 && pos < 1024)
            v = *(const half8*)&in[((size_t)b * 1024 + pos) * CIN + ch * 8];
        *(half8*)&tin[p * STRIDE + ch * 8] = v;
    }
    __syncthreads();
    const int lane = tid & 63, wave = tid >> 6;
    const int quad = lane >> 4, n = lane & 15;
    const int lrow0 = wave * 32 + n;       // wave covers l-tiles [wave*32, wave*32+32)
    floatx4 acc0[NT], acc1[NT];
#pragma unroll
    for (int t = 0; t < NT; ++t) {
        acc0[t] = (floatx4){0.f, 0.f, 0.f, 0.f};
        acc1[t] = (floatx4){0.f, 0.f, 0.f, 0.f};
    }
#pragma unroll
    for (int k = 0; k < K; ++k) {
#pragma unroll
        for (int cc = 0; cc < NCC; ++cc) {
            half8 bf0 = *(const half8*)&tin[(lrow0 + k) * STRIDE + cc * 32 + quad * 8];
            half8 bf1 = *(const half8*)&tin[(lrow0 + 16 + k) * STRIDE + cc * 32 + quad * 8];
#pragma unroll
            for (int t = 0; t < NT; ++t) {
                int f = (k * NCC + cc) * NT + t;
                half8 af = *(const half8*)&wp[((size_t)f * 64 + lane) * 8];
                acc0[t] = __builtin_amdgcn_mfma_f32_16x16x32_f16(af, bf0, acc0[t], 0, 0, 0);
                acc1[t] = __builtin_amdgcn_mfma_f32_16x16x32_f16(af, bf1, acc1[t], 0, 0, 0);
            }
        }
    }
    const int lg0 = l0b + wave * 32 + n;
#pragma unroll
    for (int t = 0; t < NT; ++t) {
        half4 hv0, hv1;
#pragma unroll
        for (int r = 0; r < 4; ++r) {
            int co = t * 16 + quad * 4 + r;
            hv0[r] = (_Float16)fmaxf(fmaf(acc0[t][r], sc[co], sh[co]), 0.f);
            hv1[r] = (_Float16)fmaxf(fmaf(acc1[t][r], sc[co], sh[co]), 0.f);
        }
        *(half4*)&out[((size_t)b * 1024 + lg0) * COUT + t * 16 + quad * 4] = hv0;
        *(half4*)&out[((size_t)b * 1024 + lg0 + 16) * COUT + t * 16 + quad * 4] = hv1;
    }
}

// ---------------- pe via MFMA -> f16 tokens ----------------
__global__ __launch_bounds__(256) void pe_mfma(
    const _Float16* __restrict__ c0b, const _Float16* __restrict__ c3b,
    const _Float16* __restrict__ wp, const float* __restrict__ bias,
    _Float16* __restrict__ outh)
{
    const int tid = threadIdx.x;
    const int w = tid >> 6, lane = tid & 63, quad = lane >> 4, col = lane & 15;
    const int s = blockIdx.x >> 1;
    const int n0 = (blockIdx.x & 1) * 64;
    const int token = n0 + w * 16 + col;
    floatx4 acc[12];
#pragma unroll
    for (int t = 0; t < 12; ++t) acc[t] = (floatx4){0.f, 0.f, 0.f, 0.f};
    for (int cc = 0; cc < 64; ++cc) {
        int rr = cc * 32 + quad * 8;
        int ktap = rr >> 8, ci = rr & 255;
        const _Float16* src = (ci < 64)
            ? c0b + ((size_t)s * 1024 + token * 8 + ktap) * 64 + ci
            : c3b + ((size_t)s * 1024 + token * 8 + ktap) * 192 + (ci - 64);
        half8 bf = *(const half8*)src;
#pragma unroll
        for (int t = 0; t < 12; ++t) {
            half8 af = *(const half8*)&wp[((size_t)(cc * 12 + t) * 64 + lane) * 8];
            acc[t] = __builtin_amdgcn_mfma_f32_16x16x32_f16(af, bf, acc[t], 0, 0, 0);
        }
    }
    const size_t tb = ((size_t)s * 128 + token) * 192;
#pragma unroll
    for (int t = 0; t < 12; ++t) {
        half4 hv;
#pragma unroll
        for (int r = 0; r < 4; ++r)
            hv[r] = (_Float16)(acc[t][r] + bias[t * 16 + quad * 4 + r]);
        *(half4*)&outh[tb + t * 16 + quad * 4] = hv;
    }
}

// ---------------- fused transformer1+2 (unchanged from round 18) ----------------
__global__ __launch_bounds__(256) void transformer12_mfma(
    const _Float16* __restrict__ src,
    const _Float16* __restrict__ wq0p, const float* __restrict__ bq0,
    const _Float16* __restrict__ wq1p, const float* __restrict__ bq1,
    _Float16* __restrict__ dst)
{
    __shared__ _Float16 uA[6400];
    __shared__ _Float16 uB[12544];
    __shared__ _Float16 sS[4608];
    __shared__ _Float16 zerobuf[16];
    const int b = blockIdx.x;
    const int tid = threadIdx.x;
    const int w = tid >> 6, lane = tid & 63, quad = lane >> 4, col = lane & 15;
    const int tok_t = tid >> 3;
    const int cc0_t = (tid & 7) * 24;
    const int h_t = (tid & 7) >> 1;
    if (tid < 16) zerobuf[tid] = (_Float16)0.f;
    float fr[24];
    half8 t0a, t0b, t0c, t1a, t1b, t1c, t2a, t2b, t2c, t3a, t3b, t3c;
    for (int pass = 0; pass < 2; ++pass) {
        const _Float16* wqkp = pass ? wq1p : wq0p;
        const float* bqk = pass ? bq1 : bq0;
        for (int i = 0; i < 4; ++i) {
            half8 s0, s1, s2;
            if (pass == 0) {
                const _Float16* srow = src + ((size_t)b * 128 + i * 32 + tok_t) * 192 + cc0_t;
                s0 = *(const half8*)&srow[0];
                s1 = *(const half8*)&srow[8];
                s2 = *(const half8*)&srow[16];
            } else {
                switch (i) {
                    case 0: s0 = t0a; s1 = t0b; s2 = t0c; break;
                    case 1: s0 = t1a; s1 = t1b; s2 = t1c; break;
                    case 2: s0 = t2a; s1 = t2b; s2 = t2c; break;
                    default: s0 = t3a; s1 = t3b; s2 = t3c; break;
                }
            }
#pragma unroll
            for (int r = 0; r < 8; ++r) {
                float v0 = (float)s0[r], v1 = (float)s1[r], v2 = (float)s2[r];
                if (i == 0) { fr[r] = v0; fr[8 + r] = v1; fr[16 + r] = v2; }
                else { fr[r] += v0; fr[8 + r] += v1; fr[16 + r] += v2; }
            }
#pragma unroll
            for (int q8 = 0; q8 < 3; ++q8) {
                half8 hv;
#pragma unroll
                for (int r = 0; r < 8; ++r) hv[r] = (_Float16)fr[q8 * 8 + r];
                *(half8*)&uA[tok_t * 200 + cc0_t + q8 * 8] = hv;
            }
            __syncthreads();
            {
                floatx4 acc2[12];
#pragma unroll
                for (int t = 0; t < 12; ++t) acc2[t] = (floatx4){0.f, 0.f, 0.f, 0.f};
#pragma unroll
                for (int ks = 0; ks < 6; ++ks) {
                    half8 a0 = *(const half8*)&uA[(col) * 200 + ks * 32 + quad * 8];
                    half8 a1 = *(const half8*)&uA[(16 + col) * 200 + ks * 32 + quad * 8];
#pragma unroll
                    for (int nl = 0; nl < 6; ++nl) {
                        int ntile = w * 6 + nl;
                        half8 bf = *(const half8*)&wqkp[((size_t)(ks * 24 + ntile) * 64 + lane) * 8];
                        acc2[nl] = __builtin_amdgcn_mfma_f32_16x16x32_f16(a0, bf, acc2[nl], 0, 0, 0);
                        acc2[6 + nl] = __builtin_amdgcn_mfma_f32_16x16x32_f16(a1, bf, acc2[6 + nl], 0, 0, 0);
                    }
                }
#pragma unroll
                for (int mt = 0; mt < 2; ++mt)
#pragma unroll
                    for (int nl = 0; nl < 6; ++nl) {
                        int j = (w * 6 + nl) * 16 + col;
                        float bv = bqk[j];
#pragma unroll
                        for (int r = 0; r < 4; ++r) {
                            int tok = mt * 16 + quad * 4 + r;
                            uB[tok * 392 + j] = (_Float16)(acc2[mt * 6 + nl][r] + bv);
                        }
                    }
                __syncthreads();
            }
            {
                const int h = w;
                floatx4 acc3[4];
#pragma unroll
                for (int t = 0; t < 4; ++t) acc3[t] = (floatx4){0.f, 0.f, 0.f, 0.f};
#pragma unroll
                for (int ks = 0; ks < 2; ++ks) {
                    bool z = (ks == 1 && quad >= 2);
                    const _Float16* pq0 = z ? zerobuf : &uB[(col) * 392 + h * 48 + ks * 32 + quad * 8];
                    const _Float16* pq1 = z ? zerobuf : &uB[(16 + col) * 392 + h * 48 + ks * 32 + quad * 8];
                    const _Float16* pk0 = z ? zerobuf : &uB[(col) * 392 + 192 + h * 48 + ks * 32 + quad * 8];
                    const _Float16* pk1 = z ? zerobuf : &uB[(16 + col) * 392 + 192 + h * 48 + ks * 32 + quad * 8];
                    half8 q0 = *(const half8*)pq0, q1 = *(const half8*)pq1;
                    half8 k0 = *(const half8*)pk0, k1 = *(const half8*)pk1;
                    acc3[0] = __builtin_amdgcn_mfma_f32_16x16x32_f16(q0, k0, acc3[0], 0, 0, 0);
                    acc3[1] = __builtin_amdgcn_mfma_f32_16x16x32_f16(q0, k1, acc3[1], 0, 0, 0);
                    acc3[2] = __builtin_amdgcn_mfma_f32_16x16x32_f16(q1, k0, acc3[2], 0, 0, 0);
                    acc3[3] = __builtin_amdgcn_mfma_f32_16x16x32_f16(q1, k1, acc3[3], 0, 0, 0);
                }
#pragma unroll
                for (int mt = 0; mt < 2; ++mt)
#pragma unroll
                    for (int nt = 0; nt < 2; ++nt)
#pragma unroll
                        for (int r = 0; r < 4; ++r) {
                            int q = mt * 16 + quad * 4 + r;
                            int k = nt * 16 + col;
                            sS[(h * 32 + q) * 36 + k] =
                                (_Float16)(acc3[mt * 2 + nt][r] * 0.14433756729740643f);
                        }
                __syncthreads();
            }
            if (tid < 128) {
                int h = tid >> 5, qi = tid & 31;
                const _Float16* row = &sS[(h * 32 + qi) * 36];
                float lg[32];
                float mx = -1e30f;
#pragma unroll
                for (int k = 0; k < 32; ++k) { lg[k] = (float)row[k]; mx = fmaxf(mx, lg[k]); }
                float sum = 0.f;
#pragma unroll
                for (int k = 0; k < 32; ++k) { lg[k] = __expf(lg[k] - mx); sum += lg[k]; }
                float inv = 1.f / sum;
                _Float16* arow = &uB[(h * 32 + qi) * 40];
#pragma unroll
                for (int k = 0; k < 32; ++k) arow[k] = (_Float16)(lg[k] * inv);
            }
            __syncthreads();
            {
                float accq[24];
#pragma unroll
                for (int q = 0; q < 24; ++q) accq[q] = 0.f;
                const _Float16* arow = &uB[(h_t * 32 + tok_t) * 40];
                for (int j = 0; j < 32; ++j) {
                    float av = (float)arow[j];
                    const half8* fp = (const half8*)&uA[j * 200 + cc0_t];
                    half8 f0 = fp[0], f1 = fp[1], f2 = fp[2];
#pragma unroll
                    for (int r = 0; r < 8; ++r) {
                        accq[r] = fmaf(av, (float)f0[r], accq[r]);
                        accq[8 + r] = fmaf(av, (float)f1[r], accq[8 + r]);
                        accq[16 + r] = fmaf(av, (float)f2[r], accq[16 + r]);
                    }
                }
#pragma unroll
                for (int q = 0; q < 24; ++q) fr[q] = accq[q];
            }
            __syncthreads();
            half8 h0, h1, h2;
#pragma unroll
            for (int r = 0; r < 8; ++r) {
                h0[r] = (_Float16)fr[r];
                h1[r] = (_Float16)fr[8 + r];
                h2[r] = (_Float16)fr[16 + r];
            }
            if (pass == 0) {
                switch (i) {
                    case 0: t0a = h0; t0b = h1; t0c = h2; break;
                    case 1: t1a = h0; t1b = h1; t1c = h2; break;
                    case 2: t2a = h0; t2b = h1; t2c = h2; break;
                    default: t3a = h0; t3b = h1; t3c = h2; break;
                }
            } else {
                _Float16* drow = dst + ((size_t)b * 128 + i * 32 + tok_t) * 192 + cc0_t;
                *(half8*)&drow[0] = h0;
                *(half8*)&drow[8] = h1;
                *(half8*)&drow[16] = h2;
            }
        }
    }
}

// ---------------- MLP via MFMA + residual + LN -> per-block token-sum partials ----------------
__global__ __launch_bounds__(256) void mlp_mfma(
    const _Float16* __restrict__ xh, const _Float16* __restrict__ a,
    const float* __restrict__ b1, const float* __restrict__ b2,
    const float* __restrict__ lng, const float* __restrict__ lnb,
    const _Float16* __restrict__ w1p, const _Float16* __restrict__ w2p,
    float* __restrict__ bsum)
{
    constexpr int HS = 296;
    __shared__ _Float16 h1s[64 * HS];
    __shared__ float b1s[264], b2s[192], lgs[192], lbs[192];
    __shared__ float ps[4 * 192];
    const int tid = threadIdx.x;
    const int w = tid >> 6, lane = tid & 63, quad = lane >> 4, col = lane & 15;
    const int tok0 = blockIdx.x * 64;
    const int tokl = w * 16 + col;
    const size_t tokg = tok0 + tokl;
    for (int i = tid; i < 264; i += 256) b1s[i] = b1[i];
    for (int i = tid; i < 192; i += 256) { b2s[i] = b2[i]; lgs[i] = lng[i]; lbs[i] = lnb[i]; }
    for (int i = tid; i < 64 * 32; i += 256) {
        int tk = i >> 5, cc2 = i & 31;
        h1s[tk * HS + 264 + cc2] = (_Float16)0.f;
    }
    __syncthreads();
    floatx4 acc1[17];
#pragma unroll
    for (int t = 0; t < 17; ++t) acc1[t] = (floatx4){0.f, 0.f, 0.f, 0.f};
#pragma unroll
    for (int ks = 0; ks < 6; ++ks) {
        half8 bf = *(const half8*)&xh[tokg * 192 + ks * 32 + quad * 8];
#pragma unroll
        for (int t = 0; t < 17; ++t) {
            half8 af = *(const half8*)&w1p[((size_t)(ks * 17 + t) * 64 + lane) * 8];
            acc1[t] = __builtin_amdgcn_mfma_f32_16x16x32_f16(af, bf, acc1[t], 0, 0, 0);
        }
    }
#pragma unroll
    for (int t = 0; t < 17; ++t) {
        int jb = t * 16 + quad * 4;
        if (jb >= 264) continue;
        half4 hv;
#pragma unroll
        for (int r = 0; r < 4; ++r) {
            int j = jb + r;
            float v = acc1[t][r] + b1s[j];
            hv[r] = (_Float16)(0.5f * v * (1.f + erff(v * 0.70710678118654752f)));
        }
        *(half4*)&h1s[tokl * HS + jb] = hv;
    }
    __syncthreads();
    floatx4 acc2[12];
#pragma unroll
    for (int t = 0; t < 12; ++t) acc2[t] = (floatx4){0.f, 0.f, 0.f, 0.f};
#pragma unroll
    for (int ks = 0; ks < 9; ++ks) {
        half8 bf = *(const half8*)&h1s[tokl * HS + ks * 32 + quad * 8];
#pragma unroll
        for (int t = 0; t < 12; ++t) {
            half8 af = *(const half8*)&w2p[((size_t)(ks * 12 + t) * 64 + lane) * 8];
            acc2[t] = __builtin_amdgcn_mfma_f32_16x16x32_f16(af, bf, acc2[t], 0, 0, 0);
        }
    }
    const size_t base = tokg * 192;
    float psum = 0.f;
#pragma unroll
    for (int t = 0; t < 12; ++t) {
        half4 av = *(const half4*)&a[base + t * 16 + quad * 4];
#pragma unroll
        for (int r = 0; r < 4; ++r) {
            float v = acc2[t][r] + b2s[t * 16 + quad * 4 + r] + (float)av[r];
            acc2[t][r] = v;
            psum += v;
        }
    }
    psum += __shfl_xor(psum, 16);
    psum += __shfl_xor(psum, 32);
    float mean = psum * (1.f / 192.f);
    float pvar = 0.f;
#pragma unroll
    for (int t = 0; t < 12; ++t)
#pragma unroll
        for (int r = 0; r < 4; ++r) {
            float d = acc2[t][r] - mean;
            pvar = fmaf(d, d, pvar);
        }
    pvar += __shfl_xor(pvar, 16);
    pvar += __shfl_xor(pvar, 32);
    float rsd = rsqrtf(pvar * (1.f / 192.f) + 1e-5f);
#pragma unroll
    for (int t = 0; t < 12; ++t) {
#pragma unroll
        for (int r = 0; r < 4; ++r) {
            float o = (acc2[t][r] - mean) * rsd * lgs[t * 16 + quad * 4 + r] + lbs[t * 16 + quad * 4 + r];
            o += __shfl_xor(o, 1);
            o += __shfl_xor(o, 2);
            o += __shfl_xor(o, 4);
            o += __shfl_xor(o, 8);
            acc2[t][r] = o;
        }
    }
    if (col == 0) {
#pragma unroll
        for (int t = 0; t < 12; ++t)
#pragma unroll
            for (int r = 0; r < 4; ++r)
                ps[w * 192 + t * 16 + quad * 4 + r] = acc2[t][r];
    }
    __syncthreads();
    if (tid < 192)
        bsum[(size_t)blockIdx.x * 192 + tid] =
            ps[tid] + ps[192 + tid] + ps[384 + tid] + ps[576 + tid];
}

// ---------------- head ----------------
__global__ __launch_bounds__(192) void head2_kernel(
    const float* __restrict__ bsum, const float* __restrict__ wcls,
    const float* __restrict__ bcls, float* __restrict__ out)
{
    __shared__ float mean[192];
    const int b = blockIdx.x;
    const int c = threadIdx.x;
    mean[c] = (bsum[(size_t)(2 * b) * 192 + c] + bsum[(size_t)(2 * b + 1) * 192 + c]) * (1.f / 128.f);
    __syncthreads();
    if (c < 3) {
        float acc = bcls[c];
        for (int k = 0; k < 192; ++k) acc = fmaf(mean[k], wcls[k * 3 + c], acc);
        out[b * 3 + c] = acc;
    }
}

static const int SZ_DICT[41] = {
    920576, 3682304, 2048, 960, 64, 64, 64, 64, 64,
    73728, 128, 128, 128, 128, 128,
    81920, 128, 128, 128, 128, 128,
    73728, 192, 192, 192, 192, 192,
    393216, 192,
    73728, 384, 73728, 384,
    50688, 264, 50688, 192,
    192, 192, 576, 3};

extern "C" void kernel_launch(void* const* d_in, const int* in_sizes, int n_in,
                              void* d_out, int out_size, void* d_ws, size_t ws_size,
                              hipStream_t stream) {
    if (n_in != 41) {
        fill_const<<<(out_size + 255) / 256, 256, 0, stream>>>((float*)d_out, out_size, 200.f);
        return;
    }
    bool mA = true;
    for (int i = 0; i < 41; ++i) mA = mA && (in_sizes[i] == SZ_DICT[i]);
    if (!mA) {
        fill_const<<<(out_size + 255) / 256, 256, 0, stream>>>((float*)d_out, out_size, 100.f);
        return;
    }
    const float* P[41];
    for (int i = 0; i < 41; ++i) P[i] = (const float*)d_in[i];

    const size_t CONVS = 100663296;
    const size_t TOKH = (size_t)512 * 128 * 192 * 2;
    const size_t WPACK = 2097152;
    const size_t ADJF = (size_t)512 * 2048 * 2;
    if (CONVS + 2 * TOKH + WPACK + ADJF > ws_size) {
        fill_const<<<(out_size + 255) / 256, 256, 0, stream>>>((float*)d_out, out_size, 50.f);
        return;
    }
    char* ws = (char*)d_ws;
    char* convS = ws;
    _Float16* pebh = (_Float16*)(ws + CONVS);
    _Float16* t2h  = (_Float16*)(ws + CONVS + TOKH);
    char* wpk = ws + CONVS + 2 * TOKH;
    _Float16* adjfull = (_Float16*)(wpk + WPACK);

    _Float16* wadjp = (_Float16*)convS;
    _Float16* xpad  = wadjp + 3735552;
    float* bsum = (float*)convS;

    const int BcC = 128;
    _Float16* c0b = (_Float16*)convS;
    char* u1 = convS + (size_t)BcC * 131072;
    char* u2 = u1 + (size_t)BcC * 393216;
    _Float16* c1b = (_Float16*)u1;
    _Float16* c2b = (_Float16*)u2;
    _Float16* c3b = (_Float16*)u1;

    _Float16* w1p  = (_Float16*)wpk;
    _Float16* w2p  = w1p + 73728;
    _Float16* w3p  = w2p + 81920;
    _Float16* wpep = w3p + 73728;
    _Float16* wq0p = wpep + 393216;
    _Float16* wq1p = wq0p + 73728;
    _Float16* wm1p = wq1p + 73728;
    _Float16* wm2p = wm1p + 52224;

    pack_all<<<21668, 256, 0, stream>>>(P[9], P[15], P[21], P[27], P[29], P[31],
                                        P[33], P[35], P[1], P[0],
                                        (_Float16*)wpk, wadjp, xpad);

    adj_mfma<<<512, 256, 0, stream>>>(xpad, wadjp, P[2], adjfull);

    for (int c = 0; c < 4; ++c) {
        const size_t b0 = (size_t)c * BcC;
        c0_tiled<<<BcC * 4, 256, 0, stream>>>(adjfull + b0 * 2048, P[3], P[4],
                                              P[5], P[6], P[7], P[8], c0b);
        conv_mfma2<64, 9, 4, 128><<<BcC * 8, 256, 0, stream>>>(c0b, w1p, P[10],
                                                 P[11], P[12], P[13], P[14], c1b);
        conv_mfma2<128, 5, 2, 128><<<BcC * 8, 256, 0, stream>>>(c1b, w2p, P[16],
                                                 P[17], P[18], P[19], P[20], c2b);
        conv_mfma2<128, 3, 1, 192><<<BcC * 8, 256, 0, stream>>>(c2b, w3p, P[22],
                                                 P[23], P[24], P[25], P[26], c3b);
        pe_mfma<<<BcC * 2, 256, 0, stream>>>(c0b, c3b, wpep, P[28],
                                             pebh + b0 * 128 * 192);
    }
    transformer12_mfma<<<512, 256, 0, stream>>>(pebh, wq0p, P[30], wq1p, P[32], t2h);
    mlp_mfma<<<1024, 256, 0, stream>>>(pebh, t2h, P[34], P[36],
                                       P[37], P[38], wm1p, wm2p, bsum);
    head2_kernel<<<512, 192, 0, stream>>>(bsum, P[39], P[40], (float*)d_out);
}

// Round 20
// 1175.275 us; speedup vs baseline: 1.2321x; 1.2321x over previous
//
#include <hip/hip_runtime.h>
#include <hip/hip_bf16.h>
#include <hip/hip_fp16.h>
#include <cstddef>

typedef _Float16 half8 __attribute__((ext_vector_type(8)));
typedef _Float16 half4 __attribute__((ext_vector_type(4)));
typedef float floatx4 __attribute__((ext_vector_type(4)));

__global__ __launch_bounds__(256) void fill_const(float* out, int n, float v) {
    int i = blockIdx.x * 256 + threadIdx.x;
    if (i < n) out[i] = v;
}

// ---------------- one-shot pack of ALL weights + x pad ----------------
__global__ __launch_bounds__(256) void pack_all(
    const float* __restrict__ wc1, const float* __restrict__ wc2,
    const float* __restrict__ wc3, const float* __restrict__ wpe,
    const float* __restrict__ wqk0, const float* __restrict__ wqk1,
    const float* __restrict__ wfc1, const float* __restrict__ wfc2,
    const float* __restrict__ wadj, const float* __restrict__ x,
    _Float16* __restrict__ wpk, _Float16* __restrict__ wadjp,
    _Float16* __restrict__ xpad)
{
    int idx = blockIdx.x * 256 + threadIdx.x;
    if (idx < 73728) {  // c1
        int i = idx;
        int j = i & 7, lane = (i >> 3) & 63, f = i >> 9;
        int t = f % 8, cc = (f / 8) % 2, k = f / 16;
        int co = t * 16 + (lane & 15);
        int ci = cc * 32 + (lane >> 4) * 8 + j;
        wpk[idx] = (_Float16)wc1[(co * 64 + ci) * 9 + k];
    } else if (idx < 155648) {  // c2
        int i = idx - 73728;
        int j = i & 7, lane = (i >> 3) & 63, f = i >> 9;
        int t = f % 8, cc = (f / 8) % 4, k = f / 32;
        int co = t * 16 + (lane & 15);
        int ci = cc * 32 + (lane >> 4) * 8 + j;
        wpk[idx] = (_Float16)wc2[(co * 128 + ci) * 5 + k];
    } else if (idx < 229376) {  // c3
        int i = idx - 155648;
        int j = i & 7, lane = (i >> 3) & 63, f = i >> 9;
        int t = f % 12, cc = (f / 12) % 4, k = f / 48;
        int co = t * 16 + (lane & 15);
        int ci = cc * 32 + (lane >> 4) * 8 + j;
        wpk[idx] = (_Float16)wc3[(co * 128 + ci) * 3 + k];
    } else if (idx < 622592) {  // pe
        int i = idx - 229376;
        int j = i & 7, lane = (i >> 3) & 63, f = i >> 9;
        int t = f % 12, cc = f / 12;
        int co = t * 16 + (lane & 15);
        int rr = cc * 32 + (lane >> 4) * 8 + j;
        int ktap = rr >> 8, ci = rr & 255;
        wpk[idx] = (_Float16)wpe[co * 2048 + ci * 8 + ktap];
    } else if (idx < 696320) {  // qk0
        int i = idx - 622592;
        int j = i & 7, lane = (i >> 3) & 63, f = i >> 9;
        int nt = f % 24, ks = f / 24;
        int c = ks * 32 + (lane >> 4) * 8 + j;
        int jcol = nt * 16 + (lane & 15);
        wpk[idx] = (_Float16)wqk0[c * 384 + jcol];
    } else if (idx < 770048) {  // qk1
        int i = idx - 696320;
        int j = i & 7, lane = (i >> 3) & 63, f = i >> 9;
        int nt = f % 24, ks = f / 24;
        int c = ks * 32 + (lane >> 4) * 8 + j;
        int jcol = nt * 16 + (lane & 15);
        wpk[idx] = (_Float16)wqk1[c * 384 + jcol];
    } else if (idx < 822272) {  // fc1 (N pad 272)
        int i = idx - 770048;
        int j = i & 7, lane = (i >> 3) & 63, f = i >> 9;
        int t = f % 17, ks = f / 17;
        int jcol = t * 16 + (lane & 15);
        int c = ks * 32 + (lane >> 4) * 8 + j;
        wpk[idx] = (jcol < 264) ? (_Float16)wfc1[c * 264 + jcol] : (_Float16)0.f;
    } else if (idx < 877568) {  // fc2 (K pad 288)
        int i = idx - 822272;
        int j = i & 7, lane = (i >> 3) & 63, f = i >> 9;
        int t = f % 12, ks = f / 12;
        int co = t * 16 + (lane & 15);
        int k = ks * 32 + (lane >> 4) * 8 + j;
        wpk[idx] = (k < 264) ? (_Float16)wfc2[k * 192 + co] : (_Float16)0.f;
    } else if (idx < 4613120) {  // adj weights (K pad 1824)
        int i = idx - 877568;
        int j = i & 7, lane = (i >> 3) & 63, f = i >> 9;
        int t = f & 127, ks = f >> 7;
        int jcol = t * 16 + (lane & 15);
        int k = ks * 32 + (lane >> 4) * 8 + j;
        wadjp[i] = (k < 1798) ? (_Float16)wadj[(size_t)k * 2048 + jcol] : (_Float16)0.f;
    } else if (idx < 5547008) {  // x pad
        int i = idx - 4613120;
        int b = i / 1824, k = i - b * 1824;
        xpad[i] = (k < 1798) ? (_Float16)x[(size_t)b * 1798 + k] : (_Float16)0.f;
    }
}

// ---------------- adj via MFMA: 256 blocks (8m x 32n), 4 n-tiles each ----------------
__global__ __launch_bounds__(256) void adj_mfma(
    const _Float16* __restrict__ xh, const _Float16* __restrict__ wp,
    const float* __restrict__ bias, _Float16* __restrict__ out)
{
    const int tid = threadIdx.x;
    const int w = tid >> 6, lane = tid & 63, quad = lane >> 4, col = lane & 15;
    const int bm = blockIdx.x >> 5;
    const int bn = blockIdx.x & 31;
    const int sample = bm * 64 + w * 16 + col;
    floatx4 acc[4];
#pragma unroll
    for (int t = 0; t < 4; ++t) acc[t] = (floatx4){0.f, 0.f, 0.f, 0.f};
    for (int ks = 0; ks < 57; ++ks) {
        half8 bf = *(const half8*)&xh[(size_t)sample * 1824 + ks * 32 + quad * 8];
#pragma unroll
        for (int tt = 0; tt < 4; ++tt) {
            int f = ks * 128 + bn * 4 + tt;
            half8 af = *(const half8*)&wp[((size_t)f * 64 + lane) * 8];
            acc[tt] = __builtin_amdgcn_mfma_f32_16x16x32_f16(af, bf, acc[tt], 0, 0, 0);
        }
    }
#pragma unroll
    for (int tt = 0; tt < 4; ++tt) {
        int jb = (bn * 4 + tt) * 16 + quad * 4;
        half4 hv;
#pragma unroll
        for (int r = 0; r < 4; ++r)
            hv[r] = (_Float16)(acc[tt][r] + bias[jb + r]);
        *(half4*)&out[(size_t)sample * 2048 + jb] = hv;
    }
}

// ---------------- c0 -> token-major [l][64] ----------------
__global__ __launch_bounds__(256) void c0_tiled(
    const _Float16* __restrict__ in, const float* __restrict__ w,
    const float* __restrict__ cb, const float* __restrict__ g,
    const float* __restrict__ bb, const float* __restrict__ m,
    const float* __restrict__ vv, _Float16* __restrict__ out)
{
    __shared__ _Float16 sin[544];
    __shared__ float wf[960], sc[64], sh[64];
    const int tid = threadIdx.x;
    const int bl = blockIdx.x >> 2;
    const int l0 = (blockIdx.x & 3) * 256;
    for (int i = tid; i < 960; i += 256) wf[i] = w[i];
    if (tid < 64) {
        float s = g[tid] * rsqrtf(vv[tid] + 1e-5f);
        sc[tid] = s;
        sh[tid] = (cb[tid] - m[tid]) * s + bb[tid];
    }
    const int base = 2 * l0 - 7;
    for (int i = tid; i < 528; i += 256) {
        int pos = base + i;
        sin[i] = (pos >= 0 && pos < 2048) ? in[(size_t)bl * 2048 + pos] : (_Float16)0.f;
    }
    __syncthreads();
    const int l = l0 + tid;
    const int s0 = 2 * tid;
    float xv[15];
#pragma unroll
    for (int k = 0; k < 15; ++k) xv[k] = (float)sin[s0 + k];
    for (int gq = 0; gq < 8; ++gq) {
        half8 ov;
#pragma unroll
        for (int r = 0; r < 8; ++r) {
            int co = gq * 8 + r;
            float acc = 0.f;
#pragma unroll
            for (int k = 0; k < 15; ++k)
                acc = fmaf(xv[k], wf[co * 15 + k], acc);
            ov[r] = (_Float16)fmaxf(fmaf(acc, sc[co], sh[co]), 0.f);
        }
        *(half8*)&out[((size_t)bl * 1024 + l) * 64 + gq * 8] = ov;
    }
}

// ---------------- conv via MFMA (round-18 proven: 64-l blocks) ----------------
template <int CIN, int K, int PAD, int COUT>
__global__ __launch_bounds__(256) void conv_mfma(
    const _Float16* __restrict__ in, const _Float16* __restrict__ wp,
    const float* __restrict__ cb, const float* __restrict__ g,
    const float* __restrict__ bb, const float* __restrict__ m,
    const float* __restrict__ vv, _Float16* __restrict__ out)
{
    constexpr int STRIDE = (CIN == 64) ? 72 : 152;
    constexpr int SPAN = 64 + K - 1;
    constexpr int NCC = CIN / 32, NT = COUT / 16, CH8 = CIN / 8;
    __shared__ _Float16 tin[SPAN * STRIDE];
    __shared__ float sc[COUT], sh[COUT];
    const int tid = threadIdx.x;
    const int b = blockIdx.x >> 4;
    const int l0b = (blockIdx.x & 15) * 64;
    for (int c = tid; c < COUT; c += 256) {
        float s = g[c] * rsqrtf(vv[c] + 1e-5f);
        sc[c] = s;
        sh[c] = (cb[c] - m[c]) * s + bb[c];
    }
    for (int idx = tid; idx < SPAN * CH8; idx += 256) {
        int p = idx / CH8, ch = idx - p * CH8;
        int pos = l0b + p - PAD;
        half8 v = {0, 0, 0, 0, 0, 0, 0, 0};
        if (pos >= 0 && pos < 1024)
            v = *(const half8*)&in[((size_t)b * 1024 + pos) * CIN + ch * 8];
        *(half8*)&tin[p * STRIDE + ch * 8] = v;
    }
    __syncthreads();
    const int lane = tid & 63, wave = tid >> 6;
    const int quad = lane >> 4, n = lane & 15;
    const int lrow0 = wave * 16 + n;
    floatx4 acc[NT];
#pragma unroll
    for (int t = 0; t < NT; ++t) acc[t] = (floatx4){0.f, 0.f, 0.f, 0.f};
#pragma unroll
    for (int k = 0; k < K; ++k) {
#pragma unroll
        for (int cc = 0; cc < NCC; ++cc) {
            half8 bfrag = *(const half8*)&tin[(lrow0 + k) * STRIDE + cc * 32 + quad * 8];
#pragma unroll
            for (int t = 0; t < NT; ++t) {
                int f = (k * NCC + cc) * NT + t;
                half8 afrag = *(const half8*)&wp[((size_t)f * 64 + lane) * 8];
                acc[t] = __builtin_amdgcn_mfma_f32_16x16x32_f16(afrag, bfrag, acc[t], 0, 0, 0);
            }
        }
    }
    const int lg = l0b + wave * 16 + n;
#pragma unroll
    for (int t = 0; t < NT; ++t) {
        half4 hv;
#pragma unroll
        for (int r = 0; r < 4; ++r) {
            int co = t * 16 + quad * 4 + r;
            hv[r] = (_Float16)fmaxf(fmaf(acc[t][r], sc[co], sh[co]), 0.f);
        }
        *(half4*)&out[((size_t)b * 1024 + lg) * COUT + t * 16 + quad * 4] = hv;
    }
}

// ---------------- pe via MFMA -> f16 tokens ----------------
__global__ __launch_bounds__(256) void pe_mfma(
    const _Float16* __restrict__ c0b, const _Float16* __restrict__ c3b,
    const _Float16* __restrict__ wp, const float* __restrict__ bias,
    _Float16* __restrict__ outh)
{
    const int tid = threadIdx.x;
    const int w = tid >> 6, lane = tid & 63, quad = lane >> 4, col = lane & 15;
    const int s = blockIdx.x >> 1;
    const int n0 = (blockIdx.x & 1) * 64;
    const int token = n0 + w * 16 + col;
    floatx4 acc[12];
#pragma unroll
    for (int t = 0; t < 12; ++t) acc[t] = (floatx4){0.f, 0.f, 0.f, 0.f};
    for (int cc = 0; cc < 64; ++cc) {
        int rr = cc * 32 + quad * 8;
        int ktap = rr >> 8, ci = rr & 255;
        const _Float16* src = (ci < 64)
            ? c0b + ((size_t)s * 1024 + token * 8 + ktap) * 64 + ci
            : c3b + ((size_t)s * 1024 + token * 8 + ktap) * 192 + (ci - 64);
        half8 bf = *(const half8*)src;
#pragma unroll
        for (int t = 0; t < 12; ++t) {
            half8 af = *(const half8*)&wp[((size_t)(cc * 12 + t) * 64 + lane) * 8];
            acc[t] = __builtin_amdgcn_mfma_f32_16x16x32_f16(af, bf, acc[t], 0, 0, 0);
        }
    }
    const size_t tb = ((size_t)s * 128 + token) * 192;
#pragma unroll
    for (int t = 0; t < 12; ++t) {
        half4 hv;
#pragma unroll
        for (int r = 0; r < 4; ++r)
            hv[r] = (_Float16)(acc[t][r] + bias[t * 16 + quad * 4 + r]);
        *(half4*)&outh[tb + t * 16 + quad * 4] = hv;
    }
}

// ---------------- fused transformer1+2 ----------------
__global__ __launch_bounds__(256) void transformer12_mfma(
    const _Float16* __restrict__ src,
    const _Float16* __restrict__ wq0p, const float* __restrict__ bq0,
    const _Float16* __restrict__ wq1p, const float* __restrict__ bq1,
    _Float16* __restrict__ dst)
{
    __shared__ _Float16 uA[6400];
    __shared__ _Float16 uB[12544];
    __shared__ _Float16 sS[4608];
    __shared__ _Float16 zerobuf[16];
    const int b = blockIdx.x;
    const int tid = threadIdx.x;
    const int w = tid >> 6, lane = tid & 63, quad = lane >> 4, col = lane & 15;
    const int tok_t = tid >> 3;
    const int cc0_t = (tid & 7) * 24;
    const int h_t = (tid & 7) >> 1;
    if (tid < 16) zerobuf[tid] = (_Float16)0.f;
    float fr[24];
    half8 t0a, t0b, t0c, t1a, t1b, t1c, t2a, t2b, t2c, t3a, t3b, t3c;
    for (int pass = 0; pass < 2; ++pass) {
        const _Float16* wqkp = pass ? wq1p : wq0p;
        const float* bqk = pass ? bq1 : bq0;
        for (int i = 0; i < 4; ++i) {
            half8 s0, s1, s2;
            if (pass == 0) {
                const _Float16* srow = src + ((size_t)b * 128 + i * 32 + tok_t) * 192 + cc0_t;
                s0 = *(const half8*)&srow[0];
                s1 = *(const half8*)&srow[8];
                s2 = *(const half8*)&srow[16];
            } else {
                switch (i) {
                    case 0: s0 = t0a; s1 = t0b; s2 = t0c; break;
                    case 1: s0 = t1a; s1 = t1b; s2 = t1c; break;
                    case 2: s0 = t2a; s1 = t2b; s2 = t2c; break;
                    default: s0 = t3a; s1 = t3b; s2 = t3c; break;
                }
            }
#pragma unroll
            for (int r = 0; r < 8; ++r) {
                float v0 = (float)s0[r], v1 = (float)s1[r], v2 = (float)s2[r];
                if (i == 0) { fr[r] = v0; fr[8 + r] = v1; fr[16 + r] = v2; }
                else { fr[r] += v0; fr[8 + r] += v1; fr[16 + r] += v2; }
            }
#pragma unroll
            for (int q8 = 0; q8 < 3; ++q8) {
                half8 hv;
#pragma unroll
                for (int r = 0; r < 8; ++r) hv[r] = (_Float16)fr[q8 * 8 + r];
                *(half8*)&uA[tok_t * 200 + cc0_t + q8 * 8] = hv;
            }
            __syncthreads();
            {
                floatx4 acc2[12];
#pragma unroll
                for (int t = 0; t < 12; ++t) acc2[t] = (floatx4){0.f, 0.f, 0.f, 0.f};
#pragma unroll
                for (int ks = 0; ks < 6; ++ks) {
                    half8 a0 = *(const half8*)&uA[(col) * 200 + ks * 32 + quad * 8];
                    half8 a1 = *(const half8*)&uA[(16 + col) * 200 + ks * 32 + quad * 8];
#pragma unroll
                    for (int nl = 0; nl < 6; ++nl) {
                        int ntile = w * 6 + nl;
                        half8 bf = *(const half8*)&wqkp[((size_t)(ks * 24 + ntile) * 64 + lane) * 8];
                        acc2[nl] = __builtin_amdgcn_mfma_f32_16x16x32_f16(a0, bf, acc2[nl], 0, 0, 0);
                        acc2[6 + nl] = __builtin_amdgcn_mfma_f32_16x16x32_f16(a1, bf, acc2[6 + nl], 0, 0, 0);
                    }
                }
#pragma unroll
                for (int mt = 0; mt < 2; ++mt)
#pragma unroll
                    for (int nl = 0; nl < 6; ++nl) {
                        int j = (w * 6 + nl) * 16 + col;
                        float bv = bqk[j];
#pragma unroll
                        for (int r = 0; r < 4; ++r) {
                            int tok = mt * 16 + quad * 4 + r;
                            uB[tok * 392 + j] = (_Float16)(acc2[mt * 6 + nl][r] + bv);
                        }
                    }
                __syncthreads();
            }
            {
                const int h = w;
                floatx4 acc3[4];
#pragma unroll
                for (int t = 0; t < 4; ++t) acc3[t] = (floatx4){0.f, 0.f, 0.f, 0.f};
#pragma unroll
                for (int ks = 0; ks < 2; ++ks) {
                    bool z = (ks == 1 && quad >= 2);
                    const _Float16* pq0 = z ? zerobuf : &uB[(col) * 392 + h * 48 + ks * 32 + quad * 8];
                    const _Float16* pq1 = z ? zerobuf : &uB[(16 + col) * 392 + h * 48 + ks * 32 + quad * 8];
                    const _Float16* pk0 = z ? zerobuf : &uB[(col) * 392 + 192 + h * 48 + ks * 32 + quad * 8];
                    const _Float16* pk1 = z ? zerobuf : &uB[(16 + col) * 392 + 192 + h * 48 + ks * 32 + quad * 8];
                    half8 q0 = *(const half8*)pq0, q1 = *(const half8*)pq1;
                    half8 k0 = *(const half8*)pk0, k1 = *(const half8*)pk1;
                    acc3[0] = __builtin_amdgcn_mfma_f32_16x16x32_f16(q0, k0, acc3[0], 0, 0, 0);
                    acc3[1] = __builtin_amdgcn_mfma_f32_16x16x32_f16(q0, k1, acc3[1], 0, 0, 0);
                    acc3[2] = __builtin_amdgcn_mfma_f32_16x16x32_f16(q1, k0, acc3[2], 0, 0, 0);
                    acc3[3] = __builtin_amdgcn_mfma_f32_16x16x32_f16(q1, k1, acc3[3], 0, 0, 0);
                }
#pragma unroll
                for (int mt = 0; mt < 2; ++mt)
#pragma unroll
                    for (int nt = 0; nt < 2; ++nt)
#pragma unroll
                        for (int r = 0; r < 4; ++r) {
                            int q = mt * 16 + quad * 4 + r;
                            int k = nt * 16 + col;
                            sS[(h * 32 + q) * 36 + k] =
                                (_Float16)(acc3[mt * 2 + nt][r] * 0.14433756729740643f);
                        }
                __syncthreads();
            }
            if (tid < 128) {
                int h = tid >> 5, qi = tid & 31;
                const _Float16* row = &sS[(h * 32 + qi) * 36];
                float lg[32];
                float mx = -1e30f;
#pragma unroll
                for (int k = 0; k < 32; ++k) { lg[k] = (float)row[k]; mx = fmaxf(mx, lg[k]); }
                float sum = 0.f;
#pragma unroll
                for (int k = 0; k < 32; ++k) { lg[k] = __expf(lg[k] - mx); sum += lg[k]; }
                float inv = 1.f / sum;
                _Float16* arow = &uB[(h * 32 + qi) * 40];
#pragma unroll
                for (int k = 0; k < 32; ++k) arow[k] = (_Float16)(lg[k] * inv);
            }
            __syncthreads();
            {
                float accq[24];
#pragma unroll
                for (int q = 0; q < 24; ++q) accq[q] = 0.f;
                const _Float16* arow = &uB[(h_t * 32 + tok_t) * 40];
                for (int j = 0; j < 32; ++j) {
                    float av = (float)arow[j];
                    const half8* fp = (const half8*)&uA[j * 200 + cc0_t];
                    half8 f0 = fp[0], f1 = fp[1], f2 = fp[2];
#pragma unroll
                    for (int r = 0; r < 8; ++r) {
                        accq[r] = fmaf(av, (float)f0[r], accq[r]);
                        accq[8 + r] = fmaf(av, (float)f1[r], accq[8 + r]);
                        accq[16 + r] = fmaf(av, (float)f2[r], accq[16 + r]);
                    }
                }
#pragma unroll
                for (int q = 0; q < 24; ++q) fr[q] = accq[q];
            }
            __syncthreads();
            half8 h0, h1, h2;
#pragma unroll
            for (int r = 0; r < 8; ++r) {
                h0[r] = (_Float16)fr[r];
                h1[r] = (_Float16)fr[8 + r];
                h2[r] = (_Float16)fr[16 + r];
            }
            if (pass == 0) {
                switch (i) {
                    case 0: t0a = h0; t0b = h1; t0c = h2; break;
                    case 1: t1a = h0; t1b = h1; t1c = h2; break;
                    case 2: t2a = h0; t2b = h1; t2c = h2; break;
                    default: t3a = h0; t3b = h1; t3c = h2; break;
                }
            } else {
                _Float16* drow = dst + ((size_t)b * 128 + i * 32 + tok_t) * 192 + cc0_t;
                *(half8*)&drow[0] = h0;
                *(half8*)&drow[8] = h1;
                *(half8*)&drow[16] = h2;
            }
        }
    }
}

// ---------------- MLP via MFMA + residual + LN -> per-block token-sum partials ----------------
__global__ __launch_bounds__(256) void mlp_mfma(
    const _Float16* __restrict__ xh, const _Float16* __restrict__ a,
    const float* __restrict__ b1, const float* __restrict__ b2,
    const float* __restrict__ lng, const float* __restrict__ lnb,
    const _Float16* __restrict__ w1p, const _Float16* __restrict__ w2p,
    float* __restrict__ bsum)
{
    constexpr int HS = 296;
    __shared__ _Float16 h1s[64 * HS];
    __shared__ float b1s[264], b2s[192], lgs[192], lbs[192];
    __shared__ float ps[4 * 192];
    const int tid = threadIdx.x;
    const int w = tid >> 6, lane = tid & 63, quad = lane >> 4, col = lane & 15;
    const int tok0 = blockIdx.x * 64;
    const int tokl = w * 16 + col;
    const size_t tokg = tok0 + tokl;
    for (int i = tid; i < 264; i += 256) b1s[i] = b1[i];
    for (int i = tid; i < 192; i += 256) { b2s[i] = b2[i]; lgs[i] = lng[i]; lbs[i] = lnb[i]; }
    for (int i = tid; i < 64 * 32; i += 256) {
        int tk = i >> 5, cc2 = i & 31;
        h1s[tk * HS + 264 + cc2] = (_Float16)0.f;
    }
    __syncthreads();
    floatx4 acc1[17];
#pragma unroll
    for (int t = 0; t < 17; ++t) acc1[t] = (floatx4){0.f, 0.f, 0.f, 0.f};
#pragma unroll
    for (int ks = 0; ks < 6; ++ks) {
        half8 bf = *(const half8*)&xh[tokg * 192 + ks * 32 + quad * 8];
#pragma unroll
        for (int t = 0; t < 17; ++t) {
            half8 af = *(const half8*)&w1p[((size_t)(ks * 17 + t) * 64 + lane) * 8];
            acc1[t] = __builtin_amdgcn_mfma_f32_16x16x32_f16(af, bf, acc1[t], 0, 0, 0);
        }
    }
#pragma unroll
    for (int t = 0; t < 17; ++t) {
        int jb = t * 16 + quad * 4;
        if (jb >= 264) continue;
        half4 hv;
#pragma unroll
        for (int r = 0; r < 4; ++r) {
            int j = jb + r;
            float v = acc1[t][r] + b1s[j];
            hv[r] = (_Float16)(0.5f * v * (1.f + erff(v * 0.70710678118654752f)));
        }
        *(half4*)&h1s[tokl * HS + jb] = hv;
    }
    __syncthreads();
    floatx4 acc2[12];
#pragma unroll
    for (int t = 0; t < 12; ++t) acc2[t] = (floatx4){0.f, 0.f, 0.f, 0.f};
#pragma unroll
    for (int ks = 0; ks < 9; ++ks) {
        half8 bf = *(const half8*)&h1s[tokl * HS + ks * 32 + quad * 8];
#pragma unroll
        for (int t = 0; t < 12; ++t) {
            half8 af = *(const half8*)&w2p[((size_t)(ks * 12 + t) * 64 + lane) * 8];
            acc2[t] = __builtin_amdgcn_mfma_f32_16x16x32_f16(af, bf, acc2[t], 0, 0, 0);
        }
    }
    const size_t base = tokg * 192;
    float psum = 0.f;
#pragma unroll
    for (int t = 0; t < 12; ++t) {
        half4 av = *(const half4*)&a[base + t * 16 + quad * 4];
#pragma unroll
        for (int r = 0; r < 4; ++r) {
            float v = acc2[t][r] + b2s[t * 16 + quad * 4 + r] + (float)av[r];
            acc2[t][r] = v;
            psum += v;
        }
    }
    psum += __shfl_xor(psum, 16);
    psum += __shfl_xor(psum, 32);
    float mean = psum * (1.f / 192.f);
    float pvar = 0.f;
#pragma unroll
    for (int t = 0; t < 12; ++t)
#pragma unroll
        for (int r = 0; r < 4; ++r) {
            float d = acc2[t][r] - mean;
            pvar = fmaf(d, d, pvar);
        }
    pvar += __shfl_xor(pvar, 16);
    pvar += __shfl_xor(pvar, 32);
    float rsd = rsqrtf(pvar * (1.f / 192.f) + 1e-5f);
#pragma unroll
    for (int t = 0; t < 12; ++t) {
#pragma unroll
        for (int r = 0; r < 4; ++r) {
            float o = (acc2[t][r] - mean) * rsd * lgs[t * 16 + quad * 4 + r] + lbs[t * 16 + quad * 4 + r];
            o += __shfl_xor(o, 1);
            o += __shfl_xor(o, 2);
            o += __shfl_xor(o, 4);
            o += __shfl_xor(o, 8);
            acc2[t][r] = o;
        }
    }
    if (col == 0) {
#pragma unroll
        for (int t = 0; t < 12; ++t)
#pragma unroll
            for (int r = 0; r < 4; ++r)
                ps[w * 192 + t * 16 + quad * 4 + r] = acc2[t][r];
    }
    __syncthreads();
    if (tid < 192)
        bsum[(size_t)blockIdx.x * 192 + tid] =
            ps[tid] + ps[192 + tid] + ps[384 + tid] + ps[576 + tid];
}

// ---------------- head ----------------
__global__ __launch_bounds__(192) void head2_kernel(
    const float* __restrict__ bsum, const float* __restrict__ wcls,
    const float* __restrict__ bcls, float* __restrict__ out)
{
    __shared__ float mean[192];
    const int b = blockIdx.x;
    const int c = threadIdx.x;
    mean[c] = (bsum[(size_t)(2 * b) * 192 + c] + bsum[(size_t)(2 * b + 1) * 192 + c]) * (1.f / 128.f);
    __syncthreads();
    if (c < 3) {
        float acc = bcls[c];
        for (int k = 0; k < 192; ++k) acc = fmaf(mean[k], wcls[k * 3 + c], acc);
        out[b * 3 + c] = acc;
    }
}

static const int SZ_DICT[41] = {
    920576, 3682304, 2048, 960, 64, 64, 64, 64, 64,
    73728, 128, 128, 128, 128, 128,
    81920, 128, 128, 128, 128, 128,
    73728, 192, 192, 192, 192, 192,
    393216, 192,
    73728, 384, 73728, 384,
    50688, 264, 50688, 192,
    192, 192, 576, 3};

extern "C" void kernel_launch(void* const* d_in, const int* in_sizes, int n_in,
                              void* d_out, int out_size, void* d_ws, size_t ws_size,
                              hipStream_t stream) {
    if (n_in != 41) {
        fill_const<<<(out_size + 255) / 256, 256, 0, stream>>>((float*)d_out, out_size, 200.f);
        return;
    }
    bool mA = true;
    for (int i = 0; i < 41; ++i) mA = mA && (in_sizes[i] == SZ_DICT[i]);
    if (!mA) {
        fill_const<<<(out_size + 255) / 256, 256, 0, stream>>>((float*)d_out, out_size, 100.f);
        return;
    }
    const float* P[41];
    for (int i = 0; i < 41; ++i) P[i] = (const float*)d_in[i];

    const size_t TOKH = (size_t)512 * 128 * 192 * 2;
    const size_t WPACK = 2097152;
    const size_t ADJF = (size_t)512 * 2048 * 2;
    // adaptive conv chunk: Bc=256 iff workspace fits (deterministic in ws_size)
    const size_t CONVS128 = 100663296;   // Bc=128 scratch
    const size_t CONVS256 = 201326592;   // Bc=256 scratch
    int BcC;
    size_t CONVS;
    if (ws_size >= CONVS256 + 2 * TOKH + WPACK + ADJF) { BcC = 256; CONVS = CONVS256; }
    else if (ws_size >= CONVS128 + 2 * TOKH + WPACK + ADJF) { BcC = 128; CONVS = CONVS128; }
    else {
        fill_const<<<(out_size + 255) / 256, 256, 0, stream>>>((float*)d_out, out_size, 50.f);
        return;
    }
    char* ws = (char*)d_ws;
    char* convS = ws;
    _Float16* pebh = (_Float16*)(ws + CONVS);
    _Float16* t2h  = (_Float16*)(ws + CONVS + TOKH);
    char* wpk = ws + CONVS + 2 * TOKH;
    _Float16* adjfull = (_Float16*)(wpk + WPACK);

    // transients in convS (dead before the region's next use)
    _Float16* wadjp = (_Float16*)convS;
    _Float16* xpad  = wadjp + 3735552;
    float* bsum = (float*)convS;

    _Float16* c0b = (_Float16*)convS;
    char* u1 = convS + (size_t)BcC * 131072;
    char* u2 = u1 + (size_t)BcC * 393216;
    _Float16* c1b = (_Float16*)u1;
    _Float16* c2b = (_Float16*)u2;
    _Float16* c3b = (_Float16*)u1;

    _Float16* w1p  = (_Float16*)wpk;
    _Float16* w2p  = w1p + 73728;
    _Float16* w3p  = w2p + 81920;
    _Float16* wpep = w3p + 73728;
    _Float16* wq0p = wpep + 393216;
    _Float16* wq1p = wq0p + 73728;
    _Float16* wm1p = wq1p + 73728;
    _Float16* wm2p = wm1p + 52224;

    pack_all<<<21668, 256, 0, stream>>>(P[9], P[15], P[21], P[27], P[29], P[31],
                                        P[33], P[35], P[1], P[0],
                                        (_Float16*)wpk, wadjp, xpad);

    adj_mfma<<<256, 256, 0, stream>>>(xpad, wadjp, P[2], adjfull);

    const int nchunk = 512 / BcC;
    for (int c = 0; c < nchunk; ++c) {
        const size_t b0 = (size_t)c * BcC;
        c0_tiled<<<BcC * 4, 256, 0, stream>>>(adjfull + b0 * 2048, P[3], P[4],
                                              P[5], P[6], P[7], P[8], c0b);
        conv_mfma<64, 9, 4, 128><<<BcC * 16, 256, 0, stream>>>(c0b, w1p, P[10],
                                                 P[11], P[12], P[13], P[14], c1b);
        conv_mfma<128, 5, 2, 128><<<BcC * 16, 256, 0, stream>>>(c1b, w2p, P[16],
                                                 P[17], P[18], P[19], P[20], c2b);
        conv_mfma<128, 3, 1, 192><<<BcC * 16, 256, 0, stream>>>(c2b, w3p, P[22],
                                                 P[23], P[24], P[25], P[26], c3b);
        pe_mfma<<<BcC * 2, 256, 0, stream>>>(c0b, c3b, wpep, P[28],
                                             pebh + b0 * 128 * 192);
    }
    transformer12_mfma<<<512, 256, 0, stream>>>(pebh, wq0p, P[30], wq1p, P[32], t2h);
    mlp_mfma<<<1024, 256, 0, stream>>>(pebh, t2h, P[34], P[36],
                                       P[37], P[38], wm1p, wm2p, bsum);
    head2_kernel<<<512, 192, 0, stream>>>(bsum, P[39], P[40], (float*)d_out);
}

// Round 21
// 1019.309 us; speedup vs baseline: 1.4207x; 1.1530x over previous
//
#include <hip/hip_runtime.h>
#include <hip/hip_bf16.h>
#include <hip/hip_fp16.h>
#include <cstddef>

typedef _Float16 half8 __attribute__((ext_vector_type(8)));
typedef _Float16 half4 __attribute__((ext_vector_type(4)));
typedef float floatx4 __attribute__((ext_vector_type(4)));
typedef float floatx16 __attribute__((ext_vector_type(16)));

__global__ __launch_bounds__(256) void fill_const(float* out, int n, float v) {
    int i = blockIdx.x * 256 + threadIdx.x;
    if (i < n) out[i] = v;
}

// ---------------- one-shot pack of ALL weights + x pad ----------------
// conv segments pack for 32x32x16 A-frags: f = ks*NW + t ;
// co = t*32 + (lane&31) ; kg = ks*16 + (lane>>5)*8 + j ; ktap = kg/CIN ; ci = kg%CIN
__global__ __launch_bounds__(256) void pack_all(
    const float* __restrict__ wc1, const float* __restrict__ wc2,
    const float* __restrict__ wc3, const float* __restrict__ wpe,
    const float* __restrict__ wqk0, const float* __restrict__ wqk1,
    const float* __restrict__ wfc1, const float* __restrict__ wfc2,
    const float* __restrict__ wadj, const float* __restrict__ x,
    _Float16* __restrict__ wpk, _Float16* __restrict__ wadjp,
    _Float16* __restrict__ xpad)
{
    int idx = blockIdx.x * 256 + threadIdx.x;
    if (idx < 73728) {  // c1: CIN=64 K=9 COUT=128 NW=4, KSEG=36
        int i = idx;
        int j = i & 7, lane = (i >> 3) & 63, f = i >> 9;
        int t = f % 4, ks = f / 4;
        int co = t * 32 + (lane & 31);
        int kg = ks * 16 + (lane >> 5) * 8 + j;
        int ktap = kg >> 6, ci = kg & 63;
        wpk[idx] = (_Float16)wc1[(co * 64 + ci) * 9 + ktap];
    } else if (idx < 155648) {  // c2: CIN=128 K=5 COUT=128 NW=4, KSEG=40
        int i = idx - 73728;
        int j = i & 7, lane = (i >> 3) & 63, f = i >> 9;
        int t = f % 4, ks = f / 4;
        int co = t * 32 + (lane & 31);
        int kg = ks * 16 + (lane >> 5) * 8 + j;
        int ktap = kg >> 7, ci = kg & 127;
        wpk[idx] = (_Float16)wc2[(co * 128 + ci) * 5 + ktap];
    } else if (idx < 229376) {  // c3: CIN=128 K=3 COUT=192 NW=6, KSEG=24
        int i = idx - 155648;
        int j = i & 7, lane = (i >> 3) & 63, f = i >> 9;
        int t = f % 6, ks = f / 6;
        int co = t * 32 + (lane & 31);
        int kg = ks * 16 + (lane >> 5) * 8 + j;
        int ktap = kg >> 7, ci = kg & 127;
        wpk[idx] = (_Float16)wc3[(co * 128 + ci) * 3 + ktap];
    } else if (idx < 622592) {  // pe (16x16x32 frags, unchanged)
        int i = idx - 229376;
        int j = i & 7, lane = (i >> 3) & 63, f = i >> 9;
        int t = f % 12, cc = f / 12;
        int co = t * 16 + (lane & 15);
        int rr = cc * 32 + (lane >> 4) * 8 + j;
        int ktap = rr >> 8, ci = rr & 255;
        wpk[idx] = (_Float16)wpe[co * 2048 + ci * 8 + ktap];
    } else if (idx < 696320) {  // qk0
        int i = idx - 622592;
        int j = i & 7, lane = (i >> 3) & 63, f = i >> 9;
        int nt = f % 24, ks = f / 24;
        int c = ks * 32 + (lane >> 4) * 8 + j;
        int jcol = nt * 16 + (lane & 15);
        wpk[idx] = (_Float16)wqk0[c * 384 + jcol];
    } else if (idx < 770048) {  // qk1
        int i = idx - 696320;
        int j = i & 7, lane = (i >> 3) & 63, f = i >> 9;
        int nt = f % 24, ks = f / 24;
        int c = ks * 32 + (lane >> 4) * 8 + j;
        int jcol = nt * 16 + (lane & 15);
        wpk[idx] = (_Float16)wqk1[c * 384 + jcol];
    } else if (idx < 822272) {  // fc1 (N pad 272)
        int i = idx - 770048;
        int j = i & 7, lane = (i >> 3) & 63, f = i >> 9;
        int t = f % 17, ks = f / 17;
        int jcol = t * 16 + (lane & 15);
        int c = ks * 32 + (lane >> 4) * 8 + j;
        wpk[idx] = (jcol < 264) ? (_Float16)wfc1[c * 264 + jcol] : (_Float16)0.f;
    } else if (idx < 877568) {  // fc2 (K pad 288)
        int i = idx - 822272;
        int j = i & 7, lane = (i >> 3) & 63, f = i >> 9;
        int t = f % 12, ks = f / 12;
        int co = t * 16 + (lane & 15);
        int k = ks * 32 + (lane >> 4) * 8 + j;
        wpk[idx] = (k < 264) ? (_Float16)wfc2[k * 192 + co] : (_Float16)0.f;
    } else if (idx < 4613120) {  // adj weights (K pad 1824)
        int i = idx - 877568;
        int j = i & 7, lane = (i >> 3) & 63, f = i >> 9;
        int t = f & 127, ks = f >> 7;
        int jcol = t * 16 + (lane & 15);
        int k = ks * 32 + (lane >> 4) * 8 + j;
        wadjp[i] = (k < 1798) ? (_Float16)wadj[(size_t)k * 2048 + jcol] : (_Float16)0.f;
    } else if (idx < 5547008) {  // x pad
        int i = idx - 4613120;
        int b = i / 1824, k = i - b * 1824;
        xpad[i] = (k < 1798) ? (_Float16)x[(size_t)b * 1798 + k] : (_Float16)0.f;
    }
}

// ---------------- adj via MFMA: 256 blocks (8m x 32n), 4 n-tiles each ----------------
__global__ __launch_bounds__(256) void adj_mfma(
    const _Float16* __restrict__ xh, const _Float16* __restrict__ wp,
    const float* __restrict__ bias, _Float16* __restrict__ out)
{
    const int tid = threadIdx.x;
    const int w = tid >> 6, lane = tid & 63, quad = lane >> 4, col = lane & 15;
    const int bm = blockIdx.x >> 5;
    const int bn = blockIdx.x & 31;
    const int sample = bm * 64 + w * 16 + col;
    floatx4 acc[4];
#pragma unroll
    for (int t = 0; t < 4; ++t) acc[t] = (floatx4){0.f, 0.f, 0.f, 0.f};
    for (int ks = 0; ks < 57; ++ks) {
        half8 bf = *(const half8*)&xh[(size_t)sample * 1824 + ks * 32 + quad * 8];
#pragma unroll
        for (int tt = 0; tt < 4; ++tt) {
            int f = ks * 128 + bn * 4 + tt;
            half8 af = *(const half8*)&wp[((size_t)f * 64 + lane) * 8];
            acc[tt] = __builtin_amdgcn_mfma_f32_16x16x32_f16(af, bf, acc[tt], 0, 0, 0);
        }
    }
#pragma unroll
    for (int tt = 0; tt < 4; ++tt) {
        int jb = (bn * 4 + tt) * 16 + quad * 4;
        half4 hv;
#pragma unroll
        for (int r = 0; r < 4; ++r)
            hv[r] = (_Float16)(acc[tt][r] + bias[jb + r]);
        *(half4*)&out[(size_t)sample * 2048 + jb] = hv;
    }
}

// ---------------- c0 -> token-major [l][64] ----------------
__global__ __launch_bounds__(256) void c0_tiled(
    const _Float16* __restrict__ in, const float* __restrict__ w,
    const float* __restrict__ cb, const float* __restrict__ g,
    const float* __restrict__ bb, const float* __restrict__ m,
    const float* __restrict__ vv, _Float16* __restrict__ out)
{
    __shared__ _Float16 sin[544];
    __shared__ float wf[960], sc[64], sh[64];
    const int tid = threadIdx.x;
    const int bl = blockIdx.x >> 2;
    const int l0 = (blockIdx.x & 3) * 256;
    for (int i = tid; i < 960; i += 256) wf[i] = w[i];
    if (tid < 64) {
        float s = g[tid] * rsqrtf(vv[tid] + 1e-5f);
        sc[tid] = s;
        sh[tid] = (cb[tid] - m[tid]) * s + bb[tid];
    }
    const int base = 2 * l0 - 7;
    for (int i = tid; i < 528; i += 256) {
        int pos = base + i;
        sin[i] = (pos >= 0 && pos < 2048) ? in[(size_t)bl * 2048 + pos] : (_Float16)0.f;
    }
    __syncthreads();
    const int l = l0 + tid;
    const int s0 = 2 * tid;
    float xv[15];
#pragma unroll
    for (int k = 0; k < 15; ++k) xv[k] = (float)sin[s0 + k];
    for (int gq = 0; gq < 8; ++gq) {
        half8 ov;
#pragma unroll
        for (int r = 0; r < 8; ++r) {
            int co = gq * 8 + r;
            float acc = 0.f;
#pragma unroll
            for (int k = 0; k < 15; ++k)
                acc = fmaf(xv[k], wf[co * 15 + k], acc);
            ov[r] = (_Float16)fmaxf(fmaf(acc, sc[co], sh[co]), 0.f);
        }
        *(half8*)&out[((size_t)bl * 1024 + l) * 64 + gq * 8] = ov;
    }
}

// ---------------- conv via MFMA 32x32x16: 32-l blocks, 1 co-tile/wave ----------------
template <int CIN, int K, int PAD, int COUT>
__global__ __launch_bounds__((COUT / 32) * 64) void conv32_mfma(
    const _Float16* __restrict__ in,   // [Bc][1024][CIN]
    const _Float16* __restrict__ wp,
    const float* __restrict__ cb, const float* __restrict__ g,
    const float* __restrict__ bb, const float* __restrict__ m,
    const float* __restrict__ vv, _Float16* __restrict__ out)  // [Bc][1024][COUT]
{
    constexpr int NW = COUT / 32;
    constexpr int NTH = NW * 64;
    constexpr int STRIDE = CIN + 8;
    constexpr int SPAN = 32 + K - 1;
    constexpr int KSEG = CIN * K / 16;
    constexpr int CH8 = CIN / 8;
    __shared__ _Float16 tin[SPAN * STRIDE];
    __shared__ float sc[COUT], sh[COUT];
    const int tid = threadIdx.x;
    const int b = blockIdx.x >> 5;
    const int l0b = (blockIdx.x & 31) * 32;
    for (int c = tid; c < COUT; c += NTH) {
        float s = g[c] * rsqrtf(vv[c] + 1e-5f);
        sc[c] = s;
        sh[c] = (cb[c] - m[c]) * s + bb[c];
    }
    for (int idx = tid; idx < SPAN * CH8; idx += NTH) {
        int p = idx / CH8, ch = idx - p * CH8;
        int pos = l0b + p - PAD;
        half8 v = {0, 0, 0, 0, 0, 0, 0, 0};
        if (pos >= 0 && pos < 1024)
            v = *(const half8*)&in[((size_t)b * 1024 + pos) * CIN + ch * 8];
        *(half8*)&tin[p * STRIDE + ch * 8] = v;
    }
    __syncthreads();
    const int lane = tid & 63, wave = tid >> 6;
    const int n32 = lane & 31, khalf = lane >> 5;
    floatx16 acc = {0.f, 0.f, 0.f, 0.f, 0.f, 0.f, 0.f, 0.f,
                    0.f, 0.f, 0.f, 0.f, 0.f, 0.f, 0.f, 0.f};
#pragma unroll
    for (int ks = 0; ks < KSEG; ++ks) {
        int kg = ks * 16;
        int ktap = kg / CIN, ci0 = kg % CIN;
        half8 bf = *(const half8*)&tin[(n32 + ktap) * STRIDE + ci0 + khalf * 8];
        half8 af = *(const half8*)&wp[((size_t)(ks * NW + wave) * 64 + lane) * 8];
        acc = __builtin_amdgcn_mfma_f32_32x32x16_f16(af, bf, acc, 0, 0, 0);
    }
    const int lg = l0b + n32;
#pragma unroll
    for (int rg = 0; rg < 4; ++rg) {
        int co = wave * 32 + 8 * rg + 4 * khalf;
        half4 hv;
#pragma unroll
        for (int r = 0; r < 4; ++r)
            hv[r] = (_Float16)fmaxf(fmaf(acc[rg * 4 + r], sc[co + r], sh[co + r]), 0.f);
        *(half4*)&out[((size_t)b * 1024 + lg) * COUT + co] = hv;
    }
}

// ---------------- pe via MFMA -> f16 tokens ----------------
__global__ __launch_bounds__(256) void pe_mfma(
    const _Float16* __restrict__ c0b, const _Float16* __restrict__ c3b,
    const _Float16* __restrict__ wp, const float* __restrict__ bias,
    _Float16* __restrict__ outh)
{
    const int tid = threadIdx.x;
    const int w = tid >> 6, lane = tid & 63, quad = lane >> 4, col = lane & 15;
    const int s = blockIdx.x >> 1;
    const int n0 = (blockIdx.x & 1) * 64;
    const int token = n0 + w * 16 + col;
    floatx4 acc[12];
#pragma unroll
    for (int t = 0; t < 12; ++t) acc[t] = (floatx4){0.f, 0.f, 0.f, 0.f};
    for (int cc = 0; cc < 64; ++cc) {
        int rr = cc * 32 + quad * 8;
        int ktap = rr >> 8, ci = rr & 255;
        const _Float16* src = (ci < 64)
            ? c0b + ((size_t)s * 1024 + token * 8 + ktap) * 64 + ci
            : c3b + ((size_t)s * 1024 + token * 8 + ktap) * 192 + (ci - 64);
        half8 bf = *(const half8*)src;
#pragma unroll
        for (int t = 0; t < 12; ++t) {
            half8 af = *(const half8*)&wp[((size_t)(cc * 12 + t) * 64 + lane) * 8];
            acc[t] = __builtin_amdgcn_mfma_f32_16x16x32_f16(af, bf, acc[t], 0, 0, 0);
        }
    }
    const size_t tb = ((size_t)s * 128 + token) * 192;
#pragma unroll
    for (int t = 0; t < 12; ++t) {
        half4 hv;
#pragma unroll
        for (int r = 0; r < 4; ++r)
            hv[r] = (_Float16)(acc[t][r] + bias[t * 16 + quad * 4 + r]);
        *(half4*)&outh[tb + t * 16 + quad * 4] = hv;
    }
}

// ---------------- fused transformer1+2 ----------------
__global__ __launch_bounds__(256) void transformer12_mfma(
    const _Float16* __restrict__ src,
    const _Float16* __restrict__ wq0p, const float* __restrict__ bq0,
    const _Float16* __restrict__ wq1p, const float* __restrict__ bq1,
    _Float16* __restrict__ dst)
{
    __shared__ _Float16 uA[6400];
    __shared__ _Float16 uB[12544];
    __shared__ _Float16 sS[4608];
    __shared__ _Float16 zerobuf[16];
    const int b = blockIdx.x;
    const int tid = threadIdx.x;
    const int w = tid >> 6, lane = tid & 63, quad = lane >> 4, col = lane & 15;
    const int tok_t = tid >> 3;
    const int cc0_t = (tid & 7) * 24;
    const int h_t = (tid & 7) >> 1;
    if (tid < 16) zerobuf[tid] = (_Float16)0.f;
    float fr[24];
    half8 t0a, t0b, t0c, t1a, t1b, t1c, t2a, t2b, t2c, t3a, t3b, t3c;
    for (int pass = 0; pass < 2; ++pass) {
        const _Float16* wqkp = pass ? wq1p : wq0p;
        const float* bqk = pass ? bq1 : bq0;
        for (int i = 0; i < 4; ++i) {
            half8 s0, s1, s2;
            if (pass == 0) {
                const _Float16* srow = src + ((size_t)b * 128 + i * 32 + tok_t) * 192 + cc0_t;
                s0 = *(const half8*)&srow[0];
                s1 = *(const half8*)&srow[8];
                s2 = *(const half8*)&srow[16];
            } else {
                switch (i) {
                    case 0: s0 = t0a; s1 = t0b; s2 = t0c; break;
                    case 1: s0 = t1a; s1 = t1b; s2 = t1c; break;
                    case 2: s0 = t2a; s1 = t2b; s2 = t2c; break;
                    default: s0 = t3a; s1 = t3b; s2 = t3c; break;
                }
            }
#pragma unroll
            for (int r = 0; r < 8; ++r) {
                float v0 = (float)s0[r], v1 = (float)s1[r], v2 = (float)s2[r];
                if (i == 0) { fr[r] = v0; fr[8 + r] = v1; fr[16 + r] = v2; }
                else { fr[r] += v0; fr[8 + r] += v1; fr[16 + r] += v2; }
            }
#pragma unroll
            for (int q8 = 0; q8 < 3; ++q8) {
                half8 hv;
#pragma unroll
                for (int r = 0; r < 8; ++r) hv[r] = (_Float16)fr[q8 * 8 + r];
                *(half8*)&uA[tok_t * 200 + cc0_t + q8 * 8] = hv;
            }
            __syncthreads();
            {
                floatx4 acc2[12];
#pragma unroll
                for (int t = 0; t < 12; ++t) acc2[t] = (floatx4){0.f, 0.f, 0.f, 0.f};
#pragma unroll
                for (int ks = 0; ks < 6; ++ks) {
                    half8 a0 = *(const half8*)&uA[(col) * 200 + ks * 32 + quad * 8];
                    half8 a1 = *(const half8*)&uA[(16 + col) * 200 + ks * 32 + quad * 8];
#pragma unroll
                    for (int nl = 0; nl < 6; ++nl) {
                        int ntile = w * 6 + nl;
                        half8 bf = *(const half8*)&wqkp[((size_t)(ks * 24 + ntile) * 64 + lane) * 8];
                        acc2[nl] = __builtin_amdgcn_mfma_f32_16x16x32_f16(a0, bf, acc2[nl], 0, 0, 0);
                        acc2[6 + nl] = __builtin_amdgcn_mfma_f32_16x16x32_f16(a1, bf, acc2[6 + nl], 0, 0, 0);
                    }
                }
#pragma unroll
                for (int mt = 0; mt < 2; ++mt)
#pragma unroll
                    for (int nl = 0; nl < 6; ++nl) {
                        int j = (w * 6 + nl) * 16 + col;
                        float bv = bqk[j];
#pragma unroll
                        for (int r = 0; r < 4; ++r) {
                            int tok = mt * 16 + quad * 4 + r;
                            uB[tok * 392 + j] = (_Float16)(acc2[mt * 6 + nl][r] + bv);
                        }
                    }
                __syncthreads();
            }
            {
                const int h = w;
                floatx4 acc3[4];
#pragma unroll
                for (int t = 0; t < 4; ++t) acc3[t] = (floatx4){0.f, 0.f, 0.f, 0.f};
#pragma unroll
                for (int ks = 0; ks < 2; ++ks) {
                    bool z = (ks == 1 && quad >= 2);
                    const _Float16* pq0 = z ? zerobuf : &uB[(col) * 392 + h * 48 + ks * 32 + quad * 8];
                    const _Float16* pq1 = z ? zerobuf : &uB[(16 + col) * 392 + h * 48 + ks * 32 + quad * 8];
                    const _Float16* pk0 = z ? zerobuf : &uB[(col) * 392 + 192 + h * 48 + ks * 32 + quad * 8];
                    const _Float16* pk1 = z ? zerobuf : &uB[(16 + col) * 392 + 192 + h * 48 + ks * 32 + quad * 8];
                    half8 q0 = *(const half8*)pq0, q1 = *(const half8*)pq1;
                    half8 k0 = *(const half8*)pk0, k1 = *(const half8*)pk1;
                    acc3[0] = __builtin_amdgcn_mfma_f32_16x16x32_f16(q0, k0, acc3[0], 0, 0, 0);
                    acc3[1] = __builtin_amdgcn_mfma_f32_16x16x32_f16(q0, k1, acc3[1], 0, 0, 0);
                    acc3[2] = __builtin_amdgcn_mfma_f32_16x16x32_f16(q1, k0, acc3[2], 0, 0, 0);
                    acc3[3] = __builtin_amdgcn_mfma_f32_16x16x32_f16(q1, k1, acc3[3], 0, 0, 0);
                }
#pragma unroll
                for (int mt = 0; mt < 2; ++mt)
#pragma unroll
                    for (int nt = 0; nt < 2; ++nt)
#pragma unroll
                        for (int r = 0; r < 4; ++r) {
                            int q = mt * 16 + quad * 4 + r;
                            int k = nt * 16 + col;
                            sS[(h * 32 + q) * 36 + k] =
                                (_Float16)(acc3[mt * 2 + nt][r] * 0.14433756729740643f);
                        }
                __syncthreads();
            }
            if (tid < 128) {
                int h = tid >> 5, qi = tid & 31;
                const _Float16* row = &sS[(h * 32 + qi) * 36];
                float lg[32];
                float mx = -1e30f;
#pragma unroll
                for (int k = 0; k < 32; ++k) { lg[k] = (float)row[k]; mx = fmaxf(mx, lg[k]); }
                float sum = 0.f;
#pragma unroll
                for (int k = 0; k < 32; ++k) { lg[k] = __expf(lg[k] - mx); sum += lg[k]; }
                float inv = 1.f / sum;
                _Float16* arow = &uB[(h * 32 + qi) * 40];
#pragma unroll
                for (int k = 0; k < 32; ++k) arow[k] = (_Float16)(lg[k] * inv);
            }
            __syncthreads();
            {
                float accq[24];
#pragma unroll
                for (int q = 0; q < 24; ++q) accq[q] = 0.f;
                const _Float16* arow = &uB[(h_t * 32 + tok_t) * 40];
                for (int j = 0; j < 32; ++j) {
                    float av = (float)arow[j];
                    const half8* fp = (const half8*)&uA[j * 200 + cc0_t];
                    half8 f0 = fp[0], f1 = fp[1], f2 = fp[2];
#pragma unroll
                    for (int r = 0; r < 8; ++r) {
                        accq[r] = fmaf(av, (float)f0[r], accq[r]);
                        accq[8 + r] = fmaf(av, (float)f1[r], accq[8 + r]);
                        accq[16 + r] = fmaf(av, (float)f2[r], accq[16 + r]);
                    }
                }
#pragma unroll
                for (int q = 0; q < 24; ++q) fr[q] = accq[q];
            }
            __syncthreads();
            half8 h0, h1, h2;
#pragma unroll
            for (int r = 0; r < 8; ++r) {
                h0[r] = (_Float16)fr[r];
                h1[r] = (_Float16)fr[8 + r];
                h2[r] = (_Float16)fr[16 + r];
            }
            if (pass == 0) {
                switch (i) {
                    case 0: t0a = h0; t0b = h1; t0c = h2; break;
                    case 1: t1a = h0; t1b = h1; t1c = h2; break;
                    case 2: t2a = h0; t2b = h1; t2c = h2; break;
                    default: t3a = h0; t3b = h1; t3c = h2; break;
                }
            } else {
                _Float16* drow = dst + ((size_t)b * 128 + i * 32 + tok_t) * 192 + cc0_t;
                *(half8*)&drow[0] = h0;
                *(half8*)&drow[8] = h1;
                *(half8*)&drow[16] = h2;
            }
        }
    }
}

// ---------------- MLP via MFMA + residual + LN -> per-block token-sum partials ----------------
__global__ __launch_bounds__(256) void mlp_mfma(
    const _Float16* __restrict__ xh, const _Float16* __restrict__ a,
    const float* __restrict__ b1, const float* __restrict__ b2,
    const float* __restrict__ lng, const float* __restrict__ lnb,
    const _Float16* __restrict__ w1p, const _Float16* __restrict__ w2p,
    float* __restrict__ bsum)
{
    constexpr int HS = 296;
    __shared__ _Float16 h1s[64 * HS];
    __shared__ float b1s[264], b2s[192], lgs[192], lbs[192];
    __shared__ float ps[4 * 192];
    const int tid = threadIdx.x;
    const int w = tid >> 6, lane = tid & 63, quad = lane >> 4, col = lane & 15;
    const int tok0 = blockIdx.x * 64;
    const int tokl = w * 16 + col;
    const size_t tokg = tok0 + tokl;
    for (int i = tid; i < 264; i += 256) b1s[i] = b1[i];
    for (int i = tid; i < 192; i += 256) { b2s[i] = b2[i]; lgs[i] = lng[i]; lbs[i] = lnb[i]; }
    for (int i = tid; i < 64 * 32; i += 256) {
        int tk = i >> 5, cc2 = i & 31;
        h1s[tk * HS + 264 + cc2] = (_Float16)0.f;
    }
    __syncthreads();
    floatx4 acc1[17];
#pragma unroll
    for (int t = 0; t < 17; ++t) acc1[t] = (floatx4){0.f, 0.f, 0.f, 0.f};
#pragma unroll
    for (int ks = 0; ks < 6; ++ks) {
        half8 bf = *(const half8*)&xh[tokg * 192 + ks * 32 + quad * 8];
#pragma unroll
        for (int t = 0; t < 17; ++t) {
            half8 af = *(const half8*)&w1p[((size_t)(ks * 17 + t) * 64 + lane) * 8];
            acc1[t] = __builtin_amdgcn_mfma_f32_16x16x32_f16(af, bf, acc1[t], 0, 0, 0);
        }
    }
#pragma unroll
    for (int t = 0; t < 17; ++t) {
        int jb = t * 16 + quad * 4;
        if (jb >= 264) continue;
        half4 hv;
#pragma unroll
        for (int r = 0; r < 4; ++r) {
            int j = jb + r;
            float v = acc1[t][r] + b1s[j];
            hv[r] = (_Float16)(0.5f * v * (1.f + erff(v * 0.70710678118654752f)));
        }
        *(half4*)&h1s[tokl * HS + jb] = hv;
    }
    __syncthreads();
    floatx4 acc2[12];
#pragma unroll
    for (int t = 0; t < 12; ++t) acc2[t] = (floatx4){0.f, 0.f, 0.f, 0.f};
#pragma unroll
    for (int ks = 0; ks < 9; ++ks) {
        half8 bf = *(const half8*)&h1s[tokl * HS + ks * 32 + quad * 8];
#pragma unroll
        for (int t = 0; t < 12; ++t) {
            half8 af = *(const half8*)&w2p[((size_t)(ks * 12 + t) * 64 + lane) * 8];
            acc2[t] = __builtin_amdgcn_mfma_f32_16x16x32_f16(af, bf, acc2[t], 0, 0, 0);
        }
    }
    const size_t base = tokg * 192;
    float psum = 0.f;
#pragma unroll
    for (int t = 0; t < 12; ++t) {
        half4 av = *(const half4*)&a[base + t * 16 + quad * 4];
#pragma unroll
        for (int r = 0; r < 4; ++r) {
            float v = acc2[t][r] + b2s[t * 16 + quad * 4 + r] + (float)av[r];
            acc2[t][r] = v;
            psum += v;
        }
    }
    psum += __shfl_xor(psum, 16);
    psum += __shfl_xor(psum, 32);
    float mean = psum * (1.f / 192.f);
    float pvar = 0.f;
#pragma unroll
    for (int t = 0; t < 12; ++t)
#pragma unroll
        for (int r = 0; r < 4; ++r) {
            float d = acc2[t][r] - mean;
            pvar = fmaf(d, d, pvar);
        }
    pvar += __shfl_xor(pvar, 16);
    pvar += __shfl_xor(pvar, 32);
    float rsd = rsqrtf(pvar * (1.f / 192.f) + 1e-5f);
#pragma unroll
    for (int t = 0; t < 12; ++t) {
#pragma unroll
        for (int r = 0; r < 4; ++r) {
            float o = (acc2[t][r] - mean) * rsd * lgs[t * 16 + quad * 4 + r] + lbs[t * 16 + quad * 4 + r];
            o += __shfl_xor(o, 1);
            o += __shfl_xor(o, 2);
            o += __shfl_xor(o, 4);
            o += __shfl_xor(o, 8);
            acc2[t][r] = o;
        }
    }
    if (col == 0) {
#pragma unroll
        for (int t = 0; t < 12; ++t)
#pragma unroll
            for (int r = 0; r < 4; ++r)
                ps[w * 192 + t * 16 + quad * 4 + r] = acc2[t][r];
    }
    __syncthreads();
    if (tid < 192)
        bsum[(size_t)blockIdx.x * 192 + tid] =
            ps[tid] + ps[192 + tid] + ps[384 + tid] + ps[576 + tid];
}

// ---------------- head ----------------
__global__ __launch_bounds__(192) void head2_kernel(
    const float* __restrict__ bsum, const float* __restrict__ wcls,
    const float* __restrict__ bcls, float* __restrict__ out)
{
    __shared__ float mean[192];
    const int b = blockIdx.x;
    const int c = threadIdx.x;
    mean[c] = (bsum[(size_t)(2 * b) * 192 + c] + bsum[(size_t)(2 * b + 1) * 192 + c]) * (1.f / 128.f);
    __syncthreads();
    if (c < 3) {
        float acc = bcls[c];
        for (int k = 0; k < 192; ++k) acc = fmaf(mean[k], wcls[k * 3 + c], acc);
        out[b * 3 + c] = acc;
    }
}

static const int SZ_DICT[41] = {
    920576, 3682304, 2048, 960, 64, 64, 64, 64, 64,
    73728, 128, 128, 128, 128, 128,
    81920, 128, 128, 128, 128, 128,
    73728, 192, 192, 192, 192, 192,
    393216, 192,
    73728, 384, 73728, 384,
    50688, 264, 50688, 192,
    192, 192, 576, 3};

extern "C" void kernel_launch(void* const* d_in, const int* in_sizes, int n_in,
                              void* d_out, int out_size, void* d_ws, size_t ws_size,
                              hipStream_t stream) {
    if (n_in != 41) {
        fill_const<<<(out_size + 255) / 256, 256, 0, stream>>>((float*)d_out, out_size, 200.f);
        return;
    }
    bool mA = true;
    for (int i = 0; i < 41; ++i) mA = mA && (in_sizes[i] == SZ_DICT[i]);
    if (!mA) {
        fill_const<<<(out_size + 255) / 256, 256, 0, stream>>>((float*)d_out, out_size, 100.f);
        return;
    }
    const float* P[41];
    for (int i = 0; i < 41; ++i) P[i] = (const float*)d_in[i];

    const size_t TOKH = (size_t)512 * 128 * 192 * 2;
    const size_t WPACK = 2097152;
    const size_t ADJF = (size_t)512 * 2048 * 2;
    const size_t CONVS128 = 100663296;
    const size_t CONVS256 = 201326592;
    int BcC;
    size_t CONVS;
    if (ws_size >= CONVS256 + 2 * TOKH + WPACK + ADJF) { BcC = 256; CONVS = CONVS256; }
    else if (ws_size >= CONVS128 + 2 * TOKH + WPACK + ADJF) { BcC = 128; CONVS = CONVS128; }
    else {
        fill_const<<<(out_size + 255) / 256, 256, 0, stream>>>((float*)d_out, out_size, 50.f);
        return;
    }
    char* ws = (char*)d_ws;
    char* convS = ws;
    _Float16* pebh = (_Float16*)(ws + CONVS);
    _Float16* t2h  = (_Float16*)(ws + CONVS + TOKH);
    char* wpk = ws + CONVS + 2 * TOKH;
    _Float16* adjfull = (_Float16*)(wpk + WPACK);

    _Float16* wadjp = (_Float16*)convS;
    _Float16* xpad  = wadjp + 3735552;
    float* bsum = (float*)convS;

    _Float16* c0b = (_Float16*)convS;
    char* u1 = convS + (size_t)BcC * 131072;
    char* u2 = u1 + (size_t)BcC * 393216;
    _Float16* c1b = (_Float16*)u1;
    _Float16* c2b = (_Float16*)u2;
    _Float16* c3b = (_Float16*)u1;

    _Float16* w1p  = (_Float16*)wpk;
    _Float16* w2p  = w1p + 73728;
    _Float16* w3p  = w2p + 81920;
    _Float16* wpep = w3p + 73728;
    _Float16* wq0p = wpep + 393216;
    _Float16* wq1p = wq0p + 73728;
    _Float16* wm1p = wq1p + 73728;
    _Float16* wm2p = wm1p + 52224;

    pack_all<<<21668, 256, 0, stream>>>(P[9], P[15], P[21], P[27], P[29], P[31],
                                        P[33], P[35], P[1], P[0],
                                        (_Float16*)wpk, wadjp, xpad);

    adj_mfma<<<256, 256, 0, stream>>>(xpad, wadjp, P[2], adjfull);

    const int nchunk = 512 / BcC;
    for (int c = 0; c < nchunk; ++c) {
        const size_t b0 = (size_t)c * BcC;
        c0_tiled<<<BcC * 4, 256, 0, stream>>>(adjfull + b0 * 2048, P[3], P[4],
                                              P[5], P[6], P[7], P[8], c0b);
        conv32_mfma<64, 9, 4, 128><<<BcC * 32, 256, 0, stream>>>(c0b, w1p, P[10],
                                                 P[11], P[12], P[13], P[14], c1b);
        conv32_mfma<128, 5, 2, 128><<<BcC * 32, 256, 0, stream>>>(c1b, w2p, P[16],
                                                 P[17], P[18], P[19], P[20], c2b);
        conv32_mfma<128, 3, 1, 192><<<BcC * 32, 384, 0, stream>>>(c2b, w3p, P[22],
                                                 P[23], P[24], P[25], P[26], c3b);
        pe_mfma<<<BcC * 2, 256, 0, stream>>>(c0b, c3b, wpep, P[28],
                                             pebh + b0 * 128 * 192);
    }
    transformer12_mfma<<<512, 256, 0, stream>>>(pebh, wq0p, P[30], wq1p, P[32], t2h);
    mlp_mfma<<<1024, 256, 0, stream>>>(pebh, t2h, P[34], P[36],
                                       P[37], P[38], wm1p, wm2p, bsum);
    head2_kernel<<<512, 192, 0, stream>>>(bsum, P[39], P[40], (float*)d_out);
}

// Round 22
// 989.567 us; speedup vs baseline: 1.4634x; 1.0301x over previous
//
#include <hip/hip_runtime.h>
#include <hip/hip_bf16.h>
#include <hip/hip_fp16.h>
#include <cstddef>

typedef _Float16 half8 __attribute__((ext_vector_type(8)));
typedef _Float16 half4 __attribute__((ext_vector_type(4)));
typedef float floatx4 __attribute__((ext_vector_type(4)));
typedef float floatx16 __attribute__((ext_vector_type(16)));

__global__ __launch_bounds__(256) void fill_const(float* out, int n, float v) {
    int i = blockIdx.x * 256 + threadIdx.x;
    if (i < n) out[i] = v;
}

// ---------------- one-shot pack of ALL weights + x pad ----------------
__global__ __launch_bounds__(256) void pack_all(
    const float* __restrict__ wc1, const float* __restrict__ wc2,
    const float* __restrict__ wc3, const float* __restrict__ wpe,
    const float* __restrict__ wqk0, const float* __restrict__ wqk1,
    const float* __restrict__ wfc1, const float* __restrict__ wfc2,
    const float* __restrict__ wadj, const float* __restrict__ x,
    _Float16* __restrict__ wpk, _Float16* __restrict__ wadjp,
    _Float16* __restrict__ xpad)
{
    int idx = blockIdx.x * 256 + threadIdx.x;
    if (idx < 73728) {  // c1: CIN=64 K=9 COUT=128 NW=4, KSEG=36 (32x32 A-frags)
        int i = idx;
        int j = i & 7, lane = (i >> 3) & 63, f = i >> 9;
        int t = f % 4, ks = f / 4;
        int co = t * 32 + (lane & 31);
        int kg = ks * 16 + (lane >> 5) * 8 + j;
        int ktap = kg >> 6, ci = kg & 63;
        wpk[idx] = (_Float16)wc1[(co * 64 + ci) * 9 + ktap];
    } else if (idx < 155648) {  // c2: CIN=128 K=5 COUT=128 NW=4, KSEG=40
        int i = idx - 73728;
        int j = i & 7, lane = (i >> 3) & 63, f = i >> 9;
        int t = f % 4, ks = f / 4;
        int co = t * 32 + (lane & 31);
        int kg = ks * 16 + (lane >> 5) * 8 + j;
        int ktap = kg >> 7, ci = kg & 127;
        wpk[idx] = (_Float16)wc2[(co * 128 + ci) * 5 + ktap];
    } else if (idx < 229376) {  // c3: CIN=128 K=3 COUT=192 NW=6, KSEG=24
        int i = idx - 155648;
        int j = i & 7, lane = (i >> 3) & 63, f = i >> 9;
        int t = f % 6, ks = f / 6;
        int co = t * 32 + (lane & 31);
        int kg = ks * 16 + (lane >> 5) * 8 + j;
        int ktap = kg >> 7, ci = kg & 127;
        wpk[idx] = (_Float16)wc3[(co * 128 + ci) * 3 + ktap];
    } else if (idx < 622592) {  // pe (16x16x32 frags)
        int i = idx - 229376;
        int j = i & 7, lane = (i >> 3) & 63, f = i >> 9;
        int t = f % 12, cc = f / 12;
        int co = t * 16 + (lane & 15);
        int rr = cc * 32 + (lane >> 4) * 8 + j;
        int ktap = rr >> 8, ci = rr & 255;
        wpk[idx] = (_Float16)wpe[co * 2048 + ci * 8 + ktap];
    } else if (idx < 696320) {  // qk0
        int i = idx - 622592;
        int j = i & 7, lane = (i >> 3) & 63, f = i >> 9;
        int nt = f % 24, ks = f / 24;
        int c = ks * 32 + (lane >> 4) * 8 + j;
        int jcol = nt * 16 + (lane & 15);
        wpk[idx] = (_Float16)wqk0[c * 384 + jcol];
    } else if (idx < 770048) {  // qk1
        int i = idx - 696320;
        int j = i & 7, lane = (i >> 3) & 63, f = i >> 9;
        int nt = f % 24, ks = f / 24;
        int c = ks * 32 + (lane >> 4) * 8 + j;
        int jcol = nt * 16 + (lane & 15);
        wpk[idx] = (_Float16)wqk1[c * 384 + jcol];
    } else if (idx < 822272) {  // fc1 (N pad 272)
        int i = idx - 770048;
        int j = i & 7, lane = (i >> 3) & 63, f = i >> 9;
        int t = f % 17, ks = f / 17;
        int jcol = t * 16 + (lane & 15);
        int c = ks * 32 + (lane >> 4) * 8 + j;
        wpk[idx] = (jcol < 264) ? (_Float16)wfc1[c * 264 + jcol] : (_Float16)0.f;
    } else if (idx < 877568) {  // fc2 (K pad 288)
        int i = idx - 822272;
        int j = i & 7, lane = (i >> 3) & 63, f = i >> 9;
        int t = f % 12, ks = f / 12;
        int co = t * 16 + (lane & 15);
        int k = ks * 32 + (lane >> 4) * 8 + j;
        wpk[idx] = (k < 264) ? (_Float16)wfc2[k * 192 + co] : (_Float16)0.f;
    } else if (idx < 4613120) {  // adj weights (K pad 1824)
        int i = idx - 877568;
        int j = i & 7, lane = (i >> 3) & 63, f = i >> 9;
        int t = f & 127, ks = f >> 7;
        int jcol = t * 16 + (lane & 15);
        int k = ks * 32 + (lane >> 4) * 8 + j;
        wadjp[i] = (k < 1798) ? (_Float16)wadj[(size_t)k * 2048 + jcol] : (_Float16)0.f;
    } else if (idx < 5547008) {  // x pad
        int i = idx - 4613120;
        int b = i / 1824, k = i - b * 1824;
        xpad[i] = (k < 1798) ? (_Float16)x[(size_t)b * 1798 + k] : (_Float16)0.f;
    }
}

// ---------------- adj via MFMA: 256 blocks (8m x 32n), 4 n-tiles each ----------------
__global__ __launch_bounds__(256) void adj_mfma(
    const _Float16* __restrict__ xh, const _Float16* __restrict__ wp,
    const float* __restrict__ bias, _Float16* __restrict__ out)
{
    const int tid = threadIdx.x;
    const int w = tid >> 6, lane = tid & 63, quad = lane >> 4, col = lane & 15;
    const int bm = blockIdx.x >> 5;
    const int bn = blockIdx.x & 31;
    const int sample = bm * 64 + w * 16 + col;
    floatx4 acc[4];
#pragma unroll
    for (int t = 0; t < 4; ++t) acc[t] = (floatx4){0.f, 0.f, 0.f, 0.f};
    for (int ks = 0; ks < 57; ++ks) {
        half8 bf = *(const half8*)&xh[(size_t)sample * 1824 + ks * 32 + quad * 8];
#pragma unroll
        for (int tt = 0; tt < 4; ++tt) {
            int f = ks * 128 + bn * 4 + tt;
            half8 af = *(const half8*)&wp[((size_t)f * 64 + lane) * 8];
            acc[tt] = __builtin_amdgcn_mfma_f32_16x16x32_f16(af, bf, acc[tt], 0, 0, 0);
        }
    }
#pragma unroll
    for (int tt = 0; tt < 4; ++tt) {
        int jb = (bn * 4 + tt) * 16 + quad * 4;
        half4 hv;
#pragma unroll
        for (int r = 0; r < 4; ++r)
            hv[r] = (_Float16)(acc[tt][r] + bias[jb + r]);
        *(half4*)&out[(size_t)sample * 2048 + jb] = hv;
    }
}

// ---------------- c0 -> token-major [l][64] ----------------
__global__ __launch_bounds__(256) void c0_tiled(
    const _Float16* __restrict__ in, const float* __restrict__ w,
    const float* __restrict__ cb, const float* __restrict__ g,
    const float* __restrict__ bb, const float* __restrict__ m,
    const float* __restrict__ vv, _Float16* __restrict__ out)
{
    __shared__ _Float16 sin[544];
    __shared__ float wf[960], sc[64], sh[64];
    const int tid = threadIdx.x;
    const int bl = blockIdx.x >> 2;
    const int l0 = (blockIdx.x & 3) * 256;
    for (int i = tid; i < 960; i += 256) wf[i] = w[i];
    if (tid < 64) {
        float s = g[tid] * rsqrtf(vv[tid] + 1e-5f);
        sc[tid] = s;
        sh[tid] = (cb[tid] - m[tid]) * s + bb[tid];
    }
    const int base = 2 * l0 - 7;
    for (int i = tid; i < 528; i += 256) {
        int pos = base + i;
        sin[i] = (pos >= 0 && pos < 2048) ? in[(size_t)bl * 2048 + pos] : (_Float16)0.f;
    }
    __syncthreads();
    const int l = l0 + tid;
    const int s0 = 2 * tid;
    float xv[15];
#pragma unroll
    for (int k = 0; k < 15; ++k) xv[k] = (float)sin[s0 + k];
    for (int gq = 0; gq < 8; ++gq) {
        half8 ov;
#pragma unroll
        for (int r = 0; r < 8; ++r) {
            int co = gq * 8 + r;
            float acc = 0.f;
#pragma unroll
            for (int k = 0; k < 15; ++k)
                acc = fmaf(xv[k], wf[co * 15 + k], acc);
            ov[r] = (_Float16)fmaxf(fmaf(acc, sc[co], sh[co]), 0.f);
        }
        *(half8*)&out[((size_t)bl * 1024 + l) * 64 + gq * 8] = ov;
    }
}

// ---------------- conv via MFMA 32x32x16 v2: 64-l blocks, 2 B-tiles per A-load ----------------
template <int CIN, int K, int PAD, int COUT>
__global__ __launch_bounds__((COUT / 32) * 64) void conv32x2(
    const _Float16* __restrict__ in,   // [Bc][1024][CIN]
    const _Float16* __restrict__ wp,
    const float* __restrict__ cb, const float* __restrict__ g,
    const float* __restrict__ bb, const float* __restrict__ m,
    const float* __restrict__ vv, _Float16* __restrict__ out)  // [Bc][1024][COUT]
{
    constexpr int NW = COUT / 32;
    constexpr int NTH = NW * 64;
    constexpr int STRIDE = CIN + 8;
    constexpr int SPAN = 64 + K - 1;
    constexpr int KSEG = CIN * K / 16;
    constexpr int CH8 = CIN / 8;
    __shared__ _Float16 tin[SPAN * STRIDE];
    __shared__ float sc[COUT], sh[COUT];
    const int tid = threadIdx.x;
    const int b = blockIdx.x >> 4;
    const int l0b = (blockIdx.x & 15) * 64;
    for (int c = tid; c < COUT; c += NTH) {
        float s = g[c] * rsqrtf(vv[c] + 1e-5f);
        sc[c] = s;
        sh[c] = (cb[c] - m[c]) * s + bb[c];
    }
    for (int idx = tid; idx < SPAN * CH8; idx += NTH) {
        int p = idx / CH8, ch = idx - p * CH8;
        int pos = l0b + p - PAD;
        half8 v = {0, 0, 0, 0, 0, 0, 0, 0};
        if (pos >= 0 && pos < 1024)
            v = *(const half8*)&in[((size_t)b * 1024 + pos) * CIN + ch * 8];
        *(half8*)&tin[p * STRIDE + ch * 8] = v;
    }
    __syncthreads();
    const int lane = tid & 63, wave = tid >> 6;
    const int n32 = lane & 31, khalf = lane >> 5;
    floatx16 acc0 = {0.f, 0.f, 0.f, 0.f, 0.f, 0.f, 0.f, 0.f,
                     0.f, 0.f, 0.f, 0.f, 0.f, 0.f, 0.f, 0.f};
    floatx16 acc1 = acc0;
#pragma unroll
    for (int ks = 0; ks < KSEG; ++ks) {
        int kg = ks * 16;
        int ktap = kg / CIN, ci0 = kg % CIN;
        half8 bf0 = *(const half8*)&tin[(n32 + ktap) * STRIDE + ci0 + khalf * 8];
        half8 bf1 = *(const half8*)&tin[(n32 + 32 + ktap) * STRIDE + ci0 + khalf * 8];
        half8 af = *(const half8*)&wp[((size_t)(ks * NW + wave) * 64 + lane) * 8];
        acc0 = __builtin_amdgcn_mfma_f32_32x32x16_f16(af, bf0, acc0, 0, 0, 0);
        acc1 = __builtin_amdgcn_mfma_f32_32x32x16_f16(af, bf1, acc1, 0, 0, 0);
    }
    const int lg = l0b + n32;
#pragma unroll
    for (int rg = 0; rg < 4; ++rg) {
        int co = wave * 32 + 8 * rg + 4 * khalf;
        half4 hv0, hv1;
#pragma unroll
        for (int r = 0; r < 4; ++r) {
            hv0[r] = (_Float16)fmaxf(fmaf(acc0[rg * 4 + r], sc[co + r], sh[co + r]), 0.f);
            hv1[r] = (_Float16)fmaxf(fmaf(acc1[rg * 4 + r], sc[co + r], sh[co + r]), 0.f);
        }
        *(half4*)&out[((size_t)b * 1024 + lg) * COUT + co] = hv0;
        *(half4*)&out[((size_t)b * 1024 + lg + 32) * COUT + co] = hv1;
    }
}

// ---------------- pe via MFMA -> f16 tokens ----------------
__global__ __launch_bounds__(256) void pe_mfma(
    const _Float16* __restrict__ c0b, const _Float16* __restrict__ c3b,
    const _Float16* __restrict__ wp, const float* __restrict__ bias,
    _Float16* __restrict__ outh)
{
    const int tid = threadIdx.x;
    const int w = tid >> 6, lane = tid & 63, quad = lane >> 4, col = lane & 15;
    const int s = blockIdx.x >> 1;
    const int n0 = (blockIdx.x & 1) * 64;
    const int token = n0 + w * 16 + col;
    floatx4 acc[12];
#pragma unroll
    for (int t = 0; t < 12; ++t) acc[t] = (floatx4){0.f, 0.f, 0.f, 0.f};
    for (int cc = 0; cc < 64; ++cc) {
        int rr = cc * 32 + quad * 8;
        int ktap = rr >> 8, ci = rr & 255;
        const _Float16* src = (ci < 64)
            ? c0b + ((size_t)s * 1024 + token * 8 + ktap) * 64 + ci
            : c3b + ((size_t)s * 1024 + token * 8 + ktap) * 192 + (ci - 64);
        half8 bf = *(const half8*)src;
#pragma unroll
        for (int t = 0; t < 12; ++t) {
            half8 af = *(const half8*)&wp[((size_t)(cc * 12 + t) * 64 + lane) * 8];
            acc[t] = __builtin_amdgcn_mfma_f32_16x16x32_f16(af, bf, acc[t], 0, 0, 0);
        }
    }
    const size_t tb = ((size_t)s * 128 + token) * 192;
#pragma unroll
    for (int t = 0; t < 12; ++t) {
        half4 hv;
#pragma unroll
        for (int r = 0; r < 4; ++r)
            hv[r] = (_Float16)(acc[t][r] + bias[t * 16 + quad * 4 + r]);
        *(half4*)&outh[tb + t * 16 + quad * 4] = hv;
    }
}

// ---------------- fused transformer1+2 ----------------
__global__ __launch_bounds__(256) void transformer12_mfma(
    const _Float16* __restrict__ src,
    const _Float16* __restrict__ wq0p, const float* __restrict__ bq0,
    const _Float16* __restrict__ wq1p, const float* __restrict__ bq1,
    _Float16* __restrict__ dst)
{
    __shared__ _Float16 uA[6400];
    __shared__ _Float16 uB[12544];
    __shared__ _Float16 sS[4608];
    __shared__ _Float16 zerobuf[16];
    const int b = blockIdx.x;
    const int tid = threadIdx.x;
    const int w = tid >> 6, lane = tid & 63, quad = lane >> 4, col = lane & 15;
    const int tok_t = tid >> 3;
    const int cc0_t = (tid & 7) * 24;
    const int h_t = (tid & 7) >> 1;
    if (tid < 16) zerobuf[tid] = (_Float16)0.f;
    float fr[24];
    half8 t0a, t0b, t0c, t1a, t1b, t1c, t2a, t2b, t2c, t3a, t3b, t3c;
    for (int pass = 0; pass < 2; ++pass) {
        const _Float16* wqkp = pass ? wq1p : wq0p;
        const float* bqk = pass ? bq1 : bq0;
        for (int i = 0; i < 4; ++i) {
            half8 s0, s1, s2;
            if (pass == 0) {
                const _Float16* srow = src + ((size_t)b * 128 + i * 32 + tok_t) * 192 + cc0_t;
                s0 = *(const half8*)&srow[0];
                s1 = *(const half8*)&srow[8];
                s2 = *(const half8*)&srow[16];
            } else {
                switch (i) {
                    case 0: s0 = t0a; s1 = t0b; s2 = t0c; break;
                    case 1: s0 = t1a; s1 = t1b; s2 = t1c; break;
                    case 2: s0 = t2a; s1 = t2b; s2 = t2c; break;
                    default: s0 = t3a; s1 = t3b; s2 = t3c; break;
                }
            }
#pragma unroll
            for (int r = 0; r < 8; ++r) {
                float v0 = (float)s0[r], v1 = (float)s1[r], v2 = (float)s2[r];
                if (i == 0) { fr[r] = v0; fr[8 + r] = v1; fr[16 + r] = v2; }
                else { fr[r] += v0; fr[8 + r] += v1; fr[16 + r] += v2; }
            }
#pragma unroll
            for (int q8 = 0; q8 < 3; ++q8) {
                half8 hv;
#pragma unroll
                for (int r = 0; r < 8; ++r) hv[r] = (_Float16)fr[q8 * 8 + r];
                *(half8*)&uA[tok_t * 200 + cc0_t + q8 * 8] = hv;
            }
            __syncthreads();
            {
                floatx4 acc2[12];
#pragma unroll
                for (int t = 0; t < 12; ++t) acc2[t] = (floatx4){0.f, 0.f, 0.f, 0.f};
#pragma unroll
                for (int ks = 0; ks < 6; ++ks) {
                    half8 a0 = *(const half8*)&uA[(col) * 200 + ks * 32 + quad * 8];
                    half8 a1 = *(const half8*)&uA[(16 + col) * 200 + ks * 32 + quad * 8];
#pragma unroll
                    for (int nl = 0; nl < 6; ++nl) {
                        int ntile = w * 6 + nl;
                        half8 bf = *(const half8*)&wqkp[((size_t)(ks * 24 + ntile) * 64 + lane) * 8];
                        acc2[nl] = __builtin_amdgcn_mfma_f32_16x16x32_f16(a0, bf, acc2[nl], 0, 0, 0);
                        acc2[6 + nl] = __builtin_amdgcn_mfma_f32_16x16x32_f16(a1, bf, acc2[6 + nl], 0, 0, 0);
                    }
                }
#pragma unroll
                for (int mt = 0; mt < 2; ++mt)
#pragma unroll
                    for (int nl = 0; nl < 6; ++nl) {
                        int j = (w * 6 + nl) * 16 + col;
                        float bv = bqk[j];
#pragma unroll
                        for (int r = 0; r < 4; ++r) {
                            int tok = mt * 16 + quad * 4 + r;
                            uB[tok * 392 + j] = (_Float16)(acc2[mt * 6 + nl][r] + bv);
                        }
                    }
                __syncthreads();
            }
            {
                const int h = w;
                floatx4 acc3[4];
#pragma unroll
                for (int t = 0; t < 4; ++t) acc3[t] = (floatx4){0.f, 0.f, 0.f, 0.f};
#pragma unroll
                for (int ks = 0; ks < 2; ++ks) {
                    bool z = (ks == 1 && quad >= 2);
                    const _Float16* pq0 = z ? zerobuf : &uB[(col) * 392 + h * 48 + ks * 32 + quad * 8];
                    const _Float16* pq1 = z ? zerobuf : &uB[(16 + col) * 392 + h * 48 + ks * 32 + quad * 8];
                    const _Float16* pk0 = z ? zerobuf : &uB[(col) * 392 + 192 + h * 48 + ks * 32 + quad * 8];
                    const _Float16* pk1 = z ? zerobuf : &uB[(16 + col) * 392 + 192 + h * 48 + ks * 32 + quad * 8];
                    half8 q0 = *(const half8*)pq0, q1 = *(const half8*)pq1;
                    half8 k0 = *(const half8*)pk0, k1 = *(const half8*)pk1;
                    acc3[0] = __builtin_amdgcn_mfma_f32_16x16x32_f16(q0, k0, acc3[0], 0, 0, 0);
                    acc3[1] = __builtin_amdgcn_mfma_f32_16x16x32_f16(q0, k1, acc3[1], 0, 0, 0);
                    acc3[2] = __builtin_amdgcn_mfma_f32_16x16x32_f16(q1, k0, acc3[2], 0, 0, 0);
                    acc3[3] = __builtin_amdgcn_mfma_f32_16x16x32_f16(q1, k1, acc3[3], 0, 0, 0);
                }
#pragma unroll
                for (int mt = 0; mt < 2; ++mt)
#pragma unroll
                    for (int nt = 0; nt < 2; ++nt)
#pragma unroll
                        for (int r = 0; r < 4; ++r) {
                            int q = mt * 16 + quad * 4 + r;
                            int k = nt * 16 + col;
                            sS[(h * 32 + q) * 36 + k] =
                                (_Float16)(acc3[mt * 2 + nt][r] * 0.14433756729740643f);
                        }
                __syncthreads();
            }
            if (tid < 128) {
                int h = tid >> 5, qi = tid & 31;
                const _Float16* row = &sS[(h * 32 + qi) * 36];
                float lg[32];
                float mx = -1e30f;
#pragma unroll
                for (int k = 0; k < 32; ++k) { lg[k] = (float)row[k]; mx = fmaxf(mx, lg[k]); }
                float sum = 0.f;
#pragma unroll
                for (int k = 0; k < 32; ++k) { lg[k] = __expf(lg[k] - mx); sum += lg[k]; }
                float inv = 1.f / sum;
                _Float16* arow = &uB[(h * 32 + qi) * 40];
#pragma unroll
                for (int k = 0; k < 32; ++k) arow[k] = (_Float16)(lg[k] * inv);
            }
            __syncthreads();
            {
                float accq[24];
#pragma unroll
                for (int q = 0; q < 24; ++q) accq[q] = 0.f;
                const _Float16* arow = &uB[(h_t * 32 + tok_t) * 40];
                for (int j = 0; j < 32; ++j) {
                    float av = (float)arow[j];
                    const half8* fp = (const half8*)&uA[j * 200 + cc0_t];
                    half8 f0 = fp[0], f1 = fp[1], f2 = fp[2];
#pragma unroll
                    for (int r = 0; r < 8; ++r) {
                        accq[r] = fmaf(av, (float)f0[r], accq[r]);
                        accq[8 + r] = fmaf(av, (float)f1[r], accq[8 + r]);
                        accq[16 + r] = fmaf(av, (float)f2[r], accq[16 + r]);
                    }
                }
#pragma unroll
                for (int q = 0; q < 24; ++q) fr[q] = accq[q];
            }
            __syncthreads();
            half8 h0, h1, h2;
#pragma unroll
            for (int r = 0; r < 8; ++r) {
                h0[r] = (_Float16)fr[r];
                h1[r] = (_Float16)fr[8 + r];
                h2[r] = (_Float16)fr[16 + r];
            }
            if (pass == 0) {
                switch (i) {
                    case 0: t0a = h0; t0b = h1; t0c = h2; break;
                    case 1: t1a = h0; t1b = h1; t1c = h2; break;
                    case 2: t2a = h0; t2b = h1; t2c = h2; break;
                    default: t3a = h0; t3b = h1; t3c = h2; break;
                }
            } else {
                _Float16* drow = dst + ((size_t)b * 128 + i * 32 + tok_t) * 192 + cc0_t;
                *(half8*)&drow[0] = h0;
                *(half8*)&drow[8] = h1;
                *(half8*)&drow[16] = h2;
            }
        }
    }
}

// ---------------- MLP via MFMA + residual + LN -> per-block token-sum partials ----------------
__global__ __launch_bounds__(256) void mlp_mfma(
    const _Float16* __restrict__ xh, const _Float16* __restrict__ a,
    const float* __restrict__ b1, const float* __restrict__ b2,
    const float* __restrict__ lng, const float* __restrict__ lnb,
    const _Float16* __restrict__ w1p, const _Float16* __restrict__ w2p,
    float* __restrict__ bsum)
{
    constexpr int HS = 296;
    __shared__ _Float16 h1s[64 * HS];
    __shared__ float b1s[264], b2s[192], lgs[192], lbs[192];
    __shared__ float ps[4 * 192];
    const int tid = threadIdx.x;
    const int w = tid >> 6, lane = tid & 63, quad = lane >> 4, col = lane & 15;
    const int tok0 = blockIdx.x * 64;
    const int tokl = w * 16 + col;
    const size_t tokg = tok0 + tokl;
    for (int i = tid; i < 264; i += 256) b1s[i] = b1[i];
    for (int i = tid; i < 192; i += 256) { b2s[i] = b2[i]; lgs[i] = lng[i]; lbs[i] = lnb[i]; }
    for (int i = tid; i < 64 * 32; i += 256) {
        int tk = i >> 5, cc2 = i & 31;
        h1s[tk * HS + 264 + cc2] = (_Float16)0.f;
    }
    __syncthreads();
    floatx4 acc1[17];
#pragma unroll
    for (int t = 0; t < 17; ++t) acc1[t] = (floatx4){0.f, 0.f, 0.f, 0.f};
#pragma unroll
    for (int ks = 0; ks < 6; ++ks) {
        half8 bf = *(const half8*)&xh[tokg * 192 + ks * 32 + quad * 8];
#pragma unroll
        for (int t = 0; t < 17; ++t) {
            half8 af = *(const half8*)&w1p[((size_t)(ks * 17 + t) * 64 + lane) * 8];
            acc1[t] = __builtin_amdgcn_mfma_f32_16x16x32_f16(af, bf, acc1[t], 0, 0, 0);
        }
    }
#pragma unroll
    for (int t = 0; t < 17; ++t) {
        int jb = t * 16 + quad * 4;
        if (jb >= 264) continue;
        half4 hv;
#pragma unroll
        for (int r = 0; r < 4; ++r) {
            int j = jb + r;
            float v = acc1[t][r] + b1s[j];
            hv[r] = (_Float16)(0.5f * v * (1.f + erff(v * 0.70710678118654752f)));
        }
        *(half4*)&h1s[tokl * HS + jb] = hv;
    }
    __syncthreads();
    floatx4 acc2[12];
#pragma unroll
    for (int t = 0; t < 12; ++t) acc2[t] = (floatx4){0.f, 0.f, 0.f, 0.f};
#pragma unroll
    for (int ks = 0; ks < 9; ++ks) {
        half8 bf = *(const half8*)&h1s[tokl * HS + ks * 32 + quad * 8];
#pragma unroll
        for (int t = 0; t < 12; ++t) {
            half8 af = *(const half8*)&w2p[((size_t)(ks * 12 + t) * 64 + lane) * 8];
            acc2[t] = __builtin_amdgcn_mfma_f32_16x16x32_f16(af, bf, acc2[t], 0, 0, 0);
        }
    }
    const size_t base = tokg * 192;
    float psum = 0.f;
#pragma unroll
    for (int t = 0; t < 12; ++t) {
        half4 av = *(const half4*)&a[base + t * 16 + quad * 4];
#pragma unroll
        for (int r = 0; r < 4; ++r) {
            float v = acc2[t][r] + b2s[t * 16 + quad * 4 + r] + (float)av[r];
            acc2[t][r] = v;
            psum += v;
        }
    }
    psum += __shfl_xor(psum, 16);
    psum += __shfl_xor(psum, 32);
    float mean = psum * (1.f / 192.f);
    float pvar = 0.f;
#pragma unroll
    for (int t = 0; t < 12; ++t)
#pragma unroll
        for (int r = 0; r < 4; ++r) {
            float d = acc2[t][r] - mean;
            pvar = fmaf(d, d, pvar);
        }
    pvar += __shfl_xor(pvar, 16);
    pvar += __shfl_xor(pvar, 32);
    float rsd = rsqrtf(pvar * (1.f / 192.f) + 1e-5f);
#pragma unroll
    for (int t = 0; t < 12; ++t) {
#pragma unroll
        for (int r = 0; r < 4; ++r) {
            float o = (acc2[t][r] - mean) * rsd * lgs[t * 16 + quad * 4 + r] + lbs[t * 16 + quad * 4 + r];
            o += __shfl_xor(o, 1);
            o += __shfl_xor(o, 2);
            o += __shfl_xor(o, 4);
            o += __shfl_xor(o, 8);
            acc2[t][r] = o;
        }
    }
    if (col == 0) {
#pragma unroll
        for (int t = 0; t < 12; ++t)
#pragma unroll
            for (int r = 0; r < 4; ++r)
                ps[w * 192 + t * 16 + quad * 4 + r] = acc2[t][r];
    }
    __syncthreads();
    if (tid < 192)
        bsum[(size_t)blockIdx.x * 192 + tid] =
            ps[tid] + ps[192 + tid] + ps[384 + tid] + ps[576 + tid];
}

// ---------------- head ----------------
__global__ __launch_bounds__(192) void head2_kernel(
    const float* __restrict__ bsum, const float* __restrict__ wcls,
    const float* __restrict__ bcls, float* __restrict__ out)
{
    __shared__ float mean[192];
    const int b = blockIdx.x;
    const int c = threadIdx.x;
    mean[c] = (bsum[(size_t)(2 * b) * 192 + c] + bsum[(size_t)(2 * b + 1) * 192 + c]) * (1.f / 128.f);
    __syncthreads();
    if (c < 3) {
        float acc = bcls[c];
        for (int k = 0; k < 192; ++k) acc = fmaf(mean[k], wcls[k * 3 + c], acc);
        out[b * 3 + c] = acc;
    }
}

static const int SZ_DICT[41] = {
    920576, 3682304, 2048, 960, 64, 64, 64, 64, 64,
    73728, 128, 128, 128, 128, 128,
    81920, 128, 128, 128, 128, 128,
    73728, 192, 192, 192, 192, 192,
    393216, 192,
    73728, 384, 73728, 384,
    50688, 264, 50688, 192,
    192, 192, 576, 3};

extern "C" void kernel_launch(void* const* d_in, const int* in_sizes, int n_in,
                              void* d_out, int out_size, void* d_ws, size_t ws_size,
                              hipStream_t stream) {
    if (n_in != 41) {
        fill_const<<<(out_size + 255) / 256, 256, 0, stream>>>((float*)d_out, out_size, 200.f);
        return;
    }
    bool mA = true;
    for (int i = 0; i < 41; ++i) mA = mA && (in_sizes[i] == SZ_DICT[i]);
    if (!mA) {
        fill_const<<<(out_size + 255) / 256, 256, 0, stream>>>((float*)d_out, out_size, 100.f);
        return;
    }
    const float* P[41];
    for (int i = 0; i < 41; ++i) P[i] = (const float*)d_in[i];

    const size_t TOKH = (size_t)512 * 128 * 192 * 2;
    const size_t WPACK = 2097152;
    const size_t ADJF = (size_t)512 * 2048 * 2;
    const size_t CONVS128 = 100663296;
    const size_t CONVS256 = 201326592;
    int BcC;
    size_t CONVS;
    if (ws_size >= CONVS256 + 2 * TOKH + WPACK + ADJF) { BcC = 256; CONVS = CONVS256; }
    else if (ws_size >= CONVS128 + 2 * TOKH + WPACK + ADJF) { BcC = 128; CONVS = CONVS128; }
    else {
        fill_const<<<(out_size + 255) / 256, 256, 0, stream>>>((float*)d_out, out_size, 50.f);
        return;
    }
    char* ws = (char*)d_ws;
    char* convS = ws;
    _Float16* pebh = (_Float16*)(ws + CONVS);
    _Float16* t2h  = (_Float16*)(ws + CONVS + TOKH);
    char* wpk = ws + CONVS + 2 * TOKH;
    _Float16* adjfull = (_Float16*)(wpk + WPACK);

    _Float16* wadjp = (_Float16*)convS;
    _Float16* xpad  = wadjp + 3735552;
    float* bsum = (float*)convS;

    _Float16* c0b = (_Float16*)convS;
    char* u1 = convS + (size_t)BcC * 131072;
    char* u2 = u1 + (size_t)BcC * 393216;
    _Float16* c1b = (_Float16*)u1;
    _Float16* c2b = (_Float16*)u2;
    _Float16* c3b = (_Float16*)u1;

    _Float16* w1p  = (_Float16*)wpk;
    _Float16* w2p  = w1p + 73728;
    _Float16* w3p  = w2p + 81920;
    _Float16* wpep = w3p + 73728;
    _Float16* wq0p = wpep + 393216;
    _Float16* wq1p = wq0p + 73728;
    _Float16* wm1p = wq1p + 73728;
    _Float16* wm2p = wm1p + 52224;

    pack_all<<<21668, 256, 0, stream>>>(P[9], P[15], P[21], P[27], P[29], P[31],
                                        P[33], P[35], P[1], P[0],
                                        (_Float16*)wpk, wadjp, xpad);

    adj_mfma<<<256, 256, 0, stream>>>(xpad, wadjp, P[2], adjfull);

    const int nchunk = 512 / BcC;
    for (int c = 0; c < nchunk; ++c) {
        const size_t b0 = (size_t)c * BcC;
        c0_tiled<<<BcC * 4, 256, 0, stream>>>(adjfull + b0 * 2048, P[3], P[4],
                                              P[5], P[6], P[7], P[8], c0b);
        conv32x2<64, 9, 4, 128><<<BcC * 16, 256, 0, stream>>>(c0b, w1p, P[10],
                                                 P[11], P[12], P[13], P[14], c1b);
        conv32x2<128, 5, 2, 128><<<BcC * 16, 256, 0, stream>>>(c1b, w2p, P[16],
                                                 P[17], P[18], P[19], P[20], c2b);
        conv32x2<128, 3, 1, 192><<<BcC * 16, 384, 0, stream>>>(c2b, w3p, P[22],
                                                 P[23], P[24], P[25], P[26], c3b);
        pe_mfma<<<BcC * 2, 256, 0, stream>>>(c0b, c3b, wpep, P[28],
                                             pebh + b0 * 128 * 192);
    }
    transformer12_mfma<<<512, 256, 0, stream>>>(pebh, wq0p, P[30], wq1p, P[32], t2h);
    mlp_mfma<<<1024, 256, 0, stream>>>(pebh, t2h, P[34], P[36],
                                       P[37], P[38], wm1p, wm2p, bsum);
    head2_kernel<<<512, 192, 0, stream>>>(bsum, P[39], P[40], (float*)d_out);
}